// Round 1
// baseline (699.005 us; speedup 1.0000x reference)
//
#include <hip/hip_runtime.h>
#include <math.h>

#define LL 3136
#define HH 56
#define WW 56
#define DI 192
#define NB 2
#define NCOUT 38
#define NKO 152
#define NST 16
#define NDTR 6
#define NCH 64     // number of scan chunks
#define CLEN 49    // LL / NCH
#define THETA_C 0.6f

__device__ __forceinline__ float siluf(float x){ return x * (1.0f / (1.0f + __expf(-x))); }
__device__ __forceinline__ float softplusf(float x){ return (x > 20.0f) ? x : log1pf(__expf(x)); }

// ---------------- K1: in_proj GEMM  xz[b][e][l] = sum_c x[b,l,c] * w[e,c] ----------------
__global__ __launch_bounds__(256) void k_inproj(const float* __restrict__ x,
                                                const float* __restrict__ w,
                                                float* __restrict__ xz){
  __shared__ float xsh[8][100];   // pad 96->100 to break bank conflicts
  int bl0 = blockIdx.x * 8;
  int tid = threadIdx.x;
  for (int i = tid; i < 8*96; i += 256){
    xsh[i/96][i%96] = x[(size_t)(bl0 + i/96)*96 + (i%96)];
  }
  __syncthreads();
  int lt = tid & 7, e0 = tid >> 3;
  int bl = bl0 + lt;
  int b = bl / LL, l = bl % LL;
  for (int j = 0; j < 12; ++j){
    int e = e0 + 32*j;
    const float* wr = w + e*96;
    float acc = 0.f;
    #pragma unroll
    for (int c = 0; c < 96; c += 4){
      acc += xsh[lt][c]*wr[c] + xsh[lt][c+1]*wr[c+1]
           + xsh[lt][c+2]*wr[c+2] + xsh[lt][c+3]*wr[c+3];
    }
    xz[((size_t)b*384 + e)*LL + l] = acc;
  }
}

// ---------------- K2: depthwise conv 3x3 + bias + SiLU on xi (first 192 ch of xz) ----------------
__global__ __launch_bounds__(256) void k_conv_xc(const float* __restrict__ xz,
                                                 const float* __restrict__ cw,
                                                 const float* __restrict__ cb,
                                                 float* __restrict__ xc){
  int idx = blockIdx.x*256 + threadIdx.x;
  if (idx >= NB*DI*LL) return;
  int l = idx % LL; int d = (idx / LL) % DI; int b = idx / (DI*LL);
  int h = l / WW, wp = l % WW;
  const float* src = xz + ((size_t)b*384 + d)*LL;
  const float* wk = cw + d*9;
  float acc = cb[d];
  #pragma unroll
  for (int dh = 0; dh < 3; ++dh){
    int hh = h + dh - 1; if (hh < 0 || hh >= HH) continue;
    const float* row = src + hh*WW;
    #pragma unroll
    for (int dw = 0; dw < 3; ++dw){
      int wq = wp + dw - 1; if (wq < 0 || wq >= WW) continue;
      acc += wk[dh*3+dw] * row[wq];
    }
  }
  xc[((size_t)b*DI + d)*LL + l] = siluf(acc);
}

// ---------------- K3: grouped conv on xt (96 groups -> 192 ch) + bias + SiLU ----------------
__global__ __launch_bounds__(256) void k_conv_xt(const float* __restrict__ xt,
                                                 const float* __restrict__ cw,
                                                 const float* __restrict__ cb,
                                                 float* __restrict__ xtc){
  int idx = blockIdx.x*256 + threadIdx.x;
  if (idx >= NB*DI*LL) return;
  int l = idx % LL; int d = (idx / LL) % DI; int b = idx / (DI*LL);
  int h = l / WW, wp = l % WW;
  int c = d >> 1;   // input channel for this output (groups=96, 2 out/ group)
  const float* wk = cw + d*9;
  float acc = cb[d];
  #pragma unroll
  for (int dh = 0; dh < 3; ++dh){
    int hh = h + dh - 1; if (hh < 0 || hh >= HH) continue;
    #pragma unroll
    for (int dw = 0; dw < 3; ++dw){
      int wq = wp + dw - 1; if (wq < 0 || wq >= WW) continue;
      acc += wk[dh*3+dw] * xt[(((size_t)b*HH + hh)*WW + wq)*96 + c];
    }
  }
  xtc[((size_t)b*DI + d)*LL + l] = siluf(acc);
}

// ---------------- K4: pools -> 4 directional sequences xs[b][k][l][d] ----------------
__global__ __launch_bounds__(256) void k_xs(const float* __restrict__ xc,
                                            const float* __restrict__ xtc,
                                            float* __restrict__ xs){
  int idx = blockIdx.x*256 + threadIdx.x;
  if (idx >= NB*DI*LL) return;
  int wp = idx % WW; int h = (idx/WW) % HH; int d = (idx/LL) % DI; int b = idx/(DI*LL);
  size_t chan = ((size_t)b*DI + d)*LL;
  // inter_col(h,wp): pool_cols of xc (wp even) or xtc (wp odd), pair (2j,2j+1), j=wp>>1
  {
    const float* src = ((wp & 1) ? xtc : xc) + chan + h*WW + ((wp>>1)*2);
    float a0 = src[0], a1 = src[1];
    float ic = 0.5f*(a0+a1) + fmaxf(a0,a1);
    int l_rc = h*WW + wp;
    xs[(((size_t)b*4 + 2)*LL + l_rc)*DI + d] = ic;                         // k=2
    xs[(((size_t)b*4 + 3)*LL + (h*WW + (WW-1-wp)))*DI + d] = ic;           // k=3 (W-flip)
  }
  // inter_row(h,wp): pool_rows of xc (h even) or xtc (h odd), rows (2i,2i+1), i=h>>1
  {
    const float* src = ((h & 1) ? xtc : xc) + chan + ((h>>1)*2)*WW + wp;
    float r0 = src[0], r1 = src[WW];
    float ir = 0.5f*(r0+r1) + fmaxf(r0,r1);
    xs[(((size_t)b*4 + 0)*LL + (wp*HH + h))*DI + d] = ir;                  // k=0 (transposed raster)
    xs[(((size_t)b*4 + 1)*LL + (wp*HH + (HH-1-h)))*DI + d] = ir;           // k=1 (H-flip)
  }
}

// ---------------- K5a: kernel_diff[ko][c] = sum over (t,3,3) of xproj_w ----------------
__global__ __launch_bounds__(256) void k_kd(const float* __restrict__ xpw, float* __restrict__ kd){
  int idx = blockIdx.x*256 + threadIdx.x;
  if (idx >= NKO*DI) return;
  const float* p = xpw + (size_t)idx*18;
  float s = 0.f;
  #pragma unroll
  for (int i = 0; i < 18; ++i) s += p[i];
  kd[idx] = s;
}

// ---------------- K5b: 3D CDC conv + temporal mean+max pool -> pooled[b][k][l][38] ----------------
__global__ __launch_bounds__(64) void k_conv3d(const float* __restrict__ xc,
                                               const float* __restrict__ xtc,
                                               const float* __restrict__ w4,
                                               const float* __restrict__ kd,
                                               float* __restrict__ pooled){
  int wp = threadIdx.x;            // 0..63, active < 56
  int h = blockIdx.y, b = blockIdx.z;
  int ko0 = blockIdx.x * 8;
  if (wp >= WW) return;
  float acc[8], od0[8], od1[8];
  #pragma unroll
  for (int j = 0; j < 8; ++j){ acc[j] = 0.f; od0[j] = 0.f; od1[j] = 0.f; }
  const float* xcb = xc + (size_t)b*DI*LL;
  const float* xtb = xtc + (size_t)b*DI*LL;
  for (int c = 0; c < DI; ++c){
    float vx[9], vt[9];
    #pragma unroll
    for (int dh = 0; dh < 3; ++dh){
      int hh = h + dh - 1;
      if (hh >= 0 && hh < HH){
        const float* rx = xcb + (size_t)c*LL + hh*WW;
        const float* rt = xtb + (size_t)c*LL + hh*WW;
        vx[dh*3+0] = (wp > 0)      ? rx[wp-1] : 0.f;
        vx[dh*3+1] = rx[wp];
        vx[dh*3+2] = (wp < WW-1)   ? rx[wp+1] : 0.f;
        vt[dh*3+0] = (wp > 0)      ? rt[wp-1] : 0.f;
        vt[dh*3+1] = rt[wp];
        vt[dh*3+2] = (wp < WW-1)   ? rt[wp+1] : 0.f;
      } else {
        vx[dh*3+0]=0.f; vx[dh*3+1]=0.f; vx[dh*3+2]=0.f;
        vt[dh*3+0]=0.f; vt[dh*3+1]=0.f; vt[dh*3+2]=0.f;
      }
    }
    float cx = vx[4], ct = vt[4];
    const float* wbase = w4 + ((size_t)ko0*DI + c)*18;   // [ko][c][t][3][3]
    const float* kdb = kd + (size_t)ko0*DI + c;
    #pragma unroll
    for (int j = 0; j < 8; ++j){
      const float* wk = wbase + (size_t)j*DI*18;
      float s = 0.f;
      #pragma unroll
      for (int q = 0; q < 9; ++q) s += wk[q]   * vx[q];
      #pragma unroll
      for (int q = 0; q < 9; ++q) s += wk[9+q] * vt[q];
      acc[j] += s;
      float kv = kdb[(size_t)j*DI];
      od0[j] += kv*cx;
      od1[j] += kv*ct;
    }
  }
  int l = h*WW + wp;
  #pragma unroll
  for (int j = 0; j < 8; ++j){
    int ko = ko0 + j;
    int k = ko / NCOUT, o = ko % NCOUT;
    // pooled = mean_t(cdc) + max_t(cdc) = 2*on - theta*(0.5*(od0+od1) + min(od0,od1))
    float pv = 2.f*acc[j] - THETA_C*(0.5f*(od0[j]+od1[j]) + fminf(od0[j], od1[j]));
    pooled[(((size_t)b*4 + k)*LL + l)*NCOUT + o] = pv;
  }
}

// ---------------- K6a: scan pass A — per-chunk (prod dA, h_end from h0=0) ----------------
__global__ __launch_bounds__(64) void k_scanA(const float* __restrict__ pooled,
                                              const float* __restrict__ xs,
                                              const float* __restrict__ dtw,
                                              const float* __restrict__ dtb,
                                              const float* __restrict__ alog,
                                              float* __restrict__ Pb,
                                              float* __restrict__ He){
  int d = blockIdx.z*64 + threadIdx.x;
  int bk = blockIdx.y;            // b*4+k
  int c = blockIdx.x;
  int k = bk & 3;
  int kdix = k*DI + d;
  float A[NST], P[NST], hst[NST];
  #pragma unroll
  for (int n = 0; n < NST; ++n){ A[n] = -__expf(alog[kdix*NST + n]); P[n] = 1.f; hst[n] = 0.f; }
  float dwv[NDTR];
  #pragma unroll
  for (int r = 0; r < NDTR; ++r) dwv[r] = dtw[kdix*NDTR + r];
  float db = dtb[kdix];
  const float* prow = pooled + ((size_t)bk*LL + c*CLEN)*NCOUT;
  const float* urow = xs + ((size_t)bk*LL + c*CLEN)*DI + d;
  for (int p = 0; p < CLEN; ++p){
    float xr = db;
    #pragma unroll
    for (int r = 0; r < NDTR; ++r) xr += prow[r]*dwv[r];
    float delta = softplusf(xr);
    float u = urow[0];
    float du = delta * u;
    #pragma unroll
    for (int n = 0; n < NST; ++n){
      float dA = __expf(delta * A[n]);
      P[n]  *= dA;
      hst[n] = dA*hst[n] + du*prow[6+n];
    }
    prow += NCOUT; urow += DI;
  }
  float* pp = Pb + (((size_t)bk*NCH + c)*DI + d)*NST;
  float* hp = He + (((size_t)bk*NCH + c)*DI + d)*NST;
  #pragma unroll
  for (int n = 0; n < NST; ++n){ pp[n] = P[n]; hp[n] = hst[n]; }
}

// ---------------- K6b: cross-chunk affine prefix -> H0 (initial state per chunk) ----------------
__global__ __launch_bounds__(256) void k_scanB(const float* __restrict__ Pb,
                                               const float* __restrict__ He,
                                               float* __restrict__ H0){
  int t = blockIdx.x*256 + threadIdx.x;
  if (t >= NB*4*DI*NST) return;
  int bk = t / (DI*NST);
  int dn = t % (DI*NST);
  float hcur = 0.f;
  for (int c = 0; c < NCH; ++c){
    size_t off = ((size_t)bk*NCH + c)*DI*NST + dn;
    H0[off] = hcur;
    hcur = Pb[off]*hcur + He[off];
  }
}

// ---------------- K6c: scan pass C — replay with h0, emit oy[b][k][l][d] ----------------
__global__ __launch_bounds__(64) void k_scanC(const float* __restrict__ pooled,
                                              const float* __restrict__ xs,
                                              const float* __restrict__ dtw,
                                              const float* __restrict__ dtb,
                                              const float* __restrict__ alog,
                                              const float* __restrict__ Dsv,
                                              const float* __restrict__ H0,
                                              float* __restrict__ oy){
  int d = blockIdx.z*64 + threadIdx.x;
  int bk = blockIdx.y;
  int c = blockIdx.x;
  int k = bk & 3;
  int kdix = k*DI + d;
  float A[NST], hst[NST];
  const float* h0p = H0 + (((size_t)bk*NCH + c)*DI + d)*NST;
  #pragma unroll
  for (int n = 0; n < NST; ++n){ A[n] = -__expf(alog[kdix*NST + n]); hst[n] = h0p[n]; }
  float dwv[NDTR];
  #pragma unroll
  for (int r = 0; r < NDTR; ++r) dwv[r] = dtw[kdix*NDTR + r];
  float db = dtb[kdix];
  float Dv = Dsv[kdix];
  const float* prow = pooled + ((size_t)bk*LL + c*CLEN)*NCOUT;
  const float* urow = xs + ((size_t)bk*LL + c*CLEN)*DI + d;
  float* orow = oy + ((size_t)bk*LL + c*CLEN)*DI + d;
  for (int p = 0; p < CLEN; ++p){
    float xr = db;
    #pragma unroll
    for (int r = 0; r < NDTR; ++r) xr += prow[r]*dwv[r];
    float delta = softplusf(xr);
    float u = urow[0];
    float du = delta * u;
    float y = 0.f;
    #pragma unroll
    for (int n = 0; n < NST; ++n){
      float dA = __expf(delta * A[n]);
      hst[n] = dA*hst[n] + du*prow[6+n];
      y += hst[n]*prow[22+n];
    }
    orow[0] = y + Dv*u;
    prow += NCOUT; urow += DI; orow += DI;
  }
}

// ---------------- K7: merge 4 directions + LayerNorm + SiLU gate + out_proj ----------------
__global__ __launch_bounds__(192) void k_out(const float* __restrict__ oy,
                                             const float* __restrict__ xz,
                                             const float* __restrict__ lng,
                                             const float* __restrict__ lnb,
                                             const float* __restrict__ opw,
                                             float* __restrict__ out){
  __shared__ float ygs[DI];
  __shared__ float redS[3], redQ[3];
  int bl = blockIdx.x; int b = bl / LL; int l = bl % LL;
  int d = threadIdx.x;
  int h = l / WW, wp = l % WW;
  int p2 = wp*HH + h;
  size_t b4 = (size_t)b*4;
  float y = oy[((b4+0)*LL + l)*DI + d]
          + oy[((b4+2)*LL + (LL-1-l))*DI + d]
          + oy[((b4+1)*LL + p2)*DI + d]
          + oy[((b4+3)*LL + (LL-1-p2))*DI + d];
  // block reduction (192 threads = 3 waves) for mean/var
  float s = y, q = y*y;
  #pragma unroll
  for (int m = 1; m < 64; m <<= 1){ s += __shfl_xor(s, m); q += __shfl_xor(q, m); }
  int wv = d >> 6;
  if ((d & 63) == 0){ redS[wv] = s; redQ[wv] = q; }
  __syncthreads();
  float S = redS[0]+redS[1]+redS[2];
  float Q = redQ[0]+redQ[1]+redQ[2];
  float mu = S * (1.f/DI);
  float var = Q * (1.f/DI) - mu*mu;
  float yn = (y - mu) * rsqrtf(var + 1e-5f) * lng[d] + lnb[d];
  float zv = xz[((size_t)b*384 + 192 + d)*LL + l];
  ygs[d] = yn * siluf(zv);
  __syncthreads();
  if (d < 96){
    const float* wr = opw + (size_t)d*DI;
    float acc = 0.f;
    #pragma unroll 4
    for (int dd = 0; dd < DI; ++dd) acc += ygs[dd]*wr[dd];
    out[(size_t)bl*96 + d] = acc;
  }
}

extern "C" void kernel_launch(void* const* d_in, const int* in_sizes, int n_in,
                              void* d_out, int out_size, void* d_ws, size_t ws_size,
                              hipStream_t stream){
  const float* x    = (const float*)d_in[0];
  const float* xt   = (const float*)d_in[1];
  const float* ipw  = (const float*)d_in[2];
  const float* c2w  = (const float*)d_in[3];
  const float* c2b  = (const float*)d_in[4];
  const float* cxw  = (const float*)d_in[5];
  const float* cxb  = (const float*)d_in[6];
  const float* xpw  = (const float*)d_in[7];
  const float* dtw  = (const float*)d_in[8];
  const float* dtb  = (const float*)d_in[9];
  const float* alog = (const float*)d_in[10];
  const float* Dsv  = (const float*)d_in[11];
  const float* lng  = (const float*)d_in[12];
  const float* lnb  = (const float*)d_in[13];
  const float* opw  = (const float*)d_in[14];
  float* out = (float*)d_out;

  float* ws   = (float*)d_ws;
  float* xz   = ws;                                   // NB*384*LL
  float* xc   = xz  + (size_t)NB*384*LL;              // NB*DI*LL
  float* xtc  = xc  + (size_t)NB*DI*LL;               // NB*DI*LL
  float* xs   = xtc + (size_t)NB*DI*LL;               // NB*4*LL*DI
  float* pool = xs  + (size_t)NB*4*LL*DI;             // NB*4*LL*NCOUT
  float* kd   = pool+ (size_t)NB*4*LL*NCOUT;          // NKO*DI
  float* Pb   = kd  + (size_t)NKO*DI;                 // NB*4*NCH*DI*NST
  float* He   = Pb  + (size_t)NB*4*NCH*DI*NST;
  float* H0   = He  + (size_t)NB*4*NCH*DI*NST;
  float* oy   = H0  + (size_t)NB*4*NCH*DI*NST;        // NB*4*LL*DI

  k_inproj<<<NB*LL/8, 256, 0, stream>>>(x, ipw, xz);
  int n1 = NB*DI*LL;
  k_conv_xc<<<(n1+255)/256, 256, 0, stream>>>(xz, c2w, c2b, xc);
  k_conv_xt<<<(n1+255)/256, 256, 0, stream>>>(xt, cxw, cxb, xtc);
  k_xs<<<(n1+255)/256, 256, 0, stream>>>(xc, xtc, xs);
  k_kd<<<(NKO*DI+255)/256, 256, 0, stream>>>(xpw, kd);
  k_conv3d<<<dim3(NKO/8, HH, NB), 64, 0, stream>>>(xc, xtc, xpw, kd, pool);
  k_scanA<<<dim3(NCH, NB*4, 3), 64, 0, stream>>>(pool, xs, dtw, dtb, alog, Pb, He);
  k_scanB<<<(NB*4*DI*NST+255)/256, 256, 0, stream>>>(Pb, He, H0);
  k_scanC<<<dim3(NCH, NB*4, 3), 64, 0, stream>>>(pool, xs, dtw, dtb, alog, Dsv, H0, oy);
  k_out<<<NB*LL, 192, 0, stream>>>(oy, xz, lng, lnb, opw, out);
}

// Round 2
// 492.976 us; speedup vs baseline: 1.4179x; 1.4179x over previous
//
#include <hip/hip_runtime.h>
#include <math.h>

#define LL 3136
#define HH 56
#define WW 56
#define DI 192
#define NB 2
#define NCOUT 38
#define NKO 152
#define NST 16
#define NDTR 6
#define NCH 64     // number of scan chunks
#define CLEN 49    // LL / NCH
#define THETA_C 0.6f

// padded A field: 58x58 pixels, K=384 (t*192+c) contiguous
#define HP 58
#define PIXP (HP*HP)          // 3364
#define KK 384
#define NPAD 160              // padded N for GEMM cols
#define AELEMS ((size_t)NB*PIXP*KK)       // 2,583,552 bf16 per array
#define BPELEMS (9*12*NPAD*32)            // 552,960 per (hi|lo)
#define BDELEMS (12*NPAD*32)              // 61,440 per (hi|lo)

typedef short s8v __attribute__((ext_vector_type(8)));
typedef float f4v __attribute__((ext_vector_type(4)));

__device__ __forceinline__ float siluf(float x){ return x * (1.0f / (1.0f + __expf(-x))); }
__device__ __forceinline__ float softplusf(float x){ return (x > 20.0f) ? x : log1pf(__expf(x)); }
__device__ __forceinline__ void split_bf16(float v, unsigned short& hi, unsigned short& lo){
  unsigned bits = __float_as_uint(v);
  hi = (unsigned short)(bits >> 16);
  float hif = __uint_as_float(((unsigned)hi) << 16);
  float lof = v - hif;
  lo = (unsigned short)(__float_as_uint(lof) >> 16);
}

// ---------------- K1: in_proj GEMM  xz[b][e][l] = sum_c x[b,l,c] * w[e,c] ----------------
__global__ __launch_bounds__(256) void k_inproj(const float* __restrict__ x,
                                                const float* __restrict__ w,
                                                float* __restrict__ xz){
  __shared__ float xsh[8][100];
  int bl0 = blockIdx.x * 8;
  int tid = threadIdx.x;
  for (int i = tid; i < 8*96; i += 256){
    xsh[i/96][i%96] = x[(size_t)(bl0 + i/96)*96 + (i%96)];
  }
  __syncthreads();
  int lt = tid & 7, e0 = tid >> 3;
  int bl = bl0 + lt;
  int b = bl / LL, l = bl % LL;
  for (int j = 0; j < 12; ++j){
    int e = e0 + 32*j;
    const float* wr = w + e*96;
    float acc = 0.f;
    #pragma unroll
    for (int c = 0; c < 96; c += 4){
      acc += xsh[lt][c]*wr[c] + xsh[lt][c+1]*wr[c+1]
           + xsh[lt][c+2]*wr[c+2] + xsh[lt][c+3]*wr[c+3];
    }
    xz[((size_t)b*384 + e)*LL + l] = acc;
  }
}

// ---------------- K2: depthwise conv 3x3 + bias + SiLU ----------------
__global__ __launch_bounds__(256) void k_conv_xc(const float* __restrict__ xz,
                                                 const float* __restrict__ cw,
                                                 const float* __restrict__ cb,
                                                 float* __restrict__ xc){
  int idx = blockIdx.x*256 + threadIdx.x;
  if (idx >= NB*DI*LL) return;
  int l = idx % LL; int d = (idx / LL) % DI; int b = idx / (DI*LL);
  int h = l / WW, wp = l % WW;
  const float* src = xz + ((size_t)b*384 + d)*LL;
  const float* wk = cw + d*9;
  float acc = cb[d];
  #pragma unroll
  for (int dh = 0; dh < 3; ++dh){
    int hh = h + dh - 1; if (hh < 0 || hh >= HH) continue;
    const float* row = src + hh*WW;
    #pragma unroll
    for (int dw = 0; dw < 3; ++dw){
      int wq = wp + dw - 1; if (wq < 0 || wq >= WW) continue;
      acc += wk[dh*3+dw] * row[wq];
    }
  }
  xc[((size_t)b*DI + d)*LL + l] = siluf(acc);
}

// ---------------- K3: grouped conv on xt ----------------
__global__ __launch_bounds__(256) void k_conv_xt(const float* __restrict__ xt,
                                                 const float* __restrict__ cw,
                                                 const float* __restrict__ cb,
                                                 float* __restrict__ xtc){
  int idx = blockIdx.x*256 + threadIdx.x;
  if (idx >= NB*DI*LL) return;
  int l = idx % LL; int d = (idx / LL) % DI; int b = idx / (DI*LL);
  int h = l / WW, wp = l % WW;
  int c = d >> 1;
  const float* wk = cw + d*9;
  float acc = cb[d];
  #pragma unroll
  for (int dh = 0; dh < 3; ++dh){
    int hh = h + dh - 1; if (hh < 0 || hh >= HH) continue;
    #pragma unroll
    for (int dw = 0; dw < 3; ++dw){
      int wq = wp + dw - 1; if (wq < 0 || wq >= WW) continue;
      acc += wk[dh*3+dw] * xt[(((size_t)b*HH + hh)*WW + wq)*96 + c];
    }
  }
  xtc[((size_t)b*DI + d)*LL + l] = siluf(acc);
}

// ---------------- K4: pools -> 4 directional sequences xs[b][k][l][d] ----------------
__global__ __launch_bounds__(256) void k_xs(const float* __restrict__ xc,
                                            const float* __restrict__ xtc,
                                            float* __restrict__ xs){
  int idx = blockIdx.x*256 + threadIdx.x;
  if (idx >= NB*DI*LL) return;
  int wp = idx % WW; int h = (idx/WW) % HH; int d = (idx/LL) % DI; int b = idx/(DI*LL);
  size_t chan = ((size_t)b*DI + d)*LL;
  {
    const float* src = ((wp & 1) ? xtc : xc) + chan + h*WW + ((wp>>1)*2);
    float a0 = src[0], a1 = src[1];
    float ic = 0.5f*(a0+a1) + fmaxf(a0,a1);
    int l_rc = h*WW + wp;
    xs[(((size_t)b*4 + 2)*LL + l_rc)*DI + d] = ic;
    xs[(((size_t)b*4 + 3)*LL + (h*WW + (WW-1-wp)))*DI + d] = ic;
  }
  {
    const float* src = ((h & 1) ? xtc : xc) + chan + ((h>>1)*2)*WW + wp;
    float r0 = src[0], r1 = src[WW];
    float ir = 0.5f*(r0+r1) + fmaxf(r0,r1);
    xs[(((size_t)b*4 + 0)*LL + (wp*HH + h))*DI + d] = ir;
    xs[(((size_t)b*4 + 1)*LL + (wp*HH + (HH-1-h)))*DI + d] = ir;
  }
}

// ---------------- K5a: kernel_diff[ko][c] = sum over (t,3,3) of xproj_w ----------------
__global__ __launch_bounds__(256) void k_kd(const float* __restrict__ xpw, float* __restrict__ kd){
  int idx = blockIdx.x*256 + threadIdx.x;
  if (idx >= NKO*DI) return;
  const float* p = xpw + (size_t)idx*18;
  float s = 0.f;
  #pragma unroll
  for (int i = 0; i < 18; ++i) s += p[i];
  kd[idx] = s;
}

// ---------------- K5b: pack weights into fragment layout, hi/lo bf16 ----------------
// Bp layout: [hl][off][ks][n][kg][j]  elem = ((off*12+ks)*160 + n)*32 + kg*8 + j
// value = 2*w4[ko=n][c][t][off] - (off==4 ? theta*kd[n][c] : 0),  k=ks*32+kg*8+j = t*192+c
// Bd layout: [hl][ks][n][kg][j] : value = (t==0 ? kd : -kd)
__global__ __launch_bounds__(256) void k_wpack(const float* __restrict__ xpw,
                                               const float* __restrict__ kd,
                                               unsigned short* __restrict__ Bp,
                                               unsigned short* __restrict__ Bd){
  int idx = blockIdx.x*256 + threadIdx.x;
  if (idx < BPELEMS){
    int q = idx & 31; int n = (idx >> 5) % NPAD; int oks = idx / (NPAD*32);
    int ks = oks % 12, off = oks / 12;
    int k = ks*32 + q;
    int t = k / DI, c = k % DI;
    float v = 0.f;
    if (n < NKO){
      float w = xpw[((size_t)(n*DI + c)*2 + t)*9 + off];
      v = 2.f*w;
      if (off == 4) v -= THETA_C * kd[n*DI + c];
    }
    unsigned short hi, lo; split_bf16(v, hi, lo);
    Bp[idx] = hi; Bp[BPELEMS + idx] = lo;
  } else {
    int id2 = idx - BPELEMS;
    if (id2 >= BDELEMS) return;
    int q = id2 & 31; int n = (id2 >> 5) % NPAD; int ks = id2 / (NPAD*32);
    int k = ks*32 + q;
    int t = k / DI, c = k % DI;
    float v = 0.f;
    if (n < NKO){
      float kv = kd[n*DI + c];
      v = (t == 0) ? kv : -kv;
    }
    unsigned short hi, lo; split_bf16(v, hi, lo);
    Bd[id2] = hi; Bd[BDELEMS + id2] = lo;
  }
}

// ---------------- K5c: pack A (padded 58x58, K contiguous), hi/lo bf16 ----------------
// Ah/Al[b][pix][k], pix = (h+1)*58 + (wp+1), k = t*192+c. Borders pre-zeroed by memset.
__global__ __launch_bounds__(256) void k_apack(const float* __restrict__ xc,
                                               const float* __restrict__ xtc,
                                               unsigned short* __restrict__ Ah,
                                               unsigned short* __restrict__ Al){
  __shared__ float tile[64*57];
  int h = blockIdx.x, b = blockIdx.y;
  int tid = threadIdx.x;
  int cl = tid & 63, wv = tid >> 6;
  for (int t = 0; t < 2; ++t){
    const float* src = (t ? xtc : xc) + (size_t)b*DI*LL;
    for (int cc = 0; cc < 3; ++cc){
      for (int i = tid; i < 64*56; i += 256){
        int ci = i / 56, wpx = i % 56;
        tile[ci*57 + wpx] = src[(size_t)(cc*64 + ci)*LL + h*WW + wpx];
      }
      __syncthreads();
      for (int wp = wv; wp < WW; wp += 4){
        float v = tile[cl*57 + wp];
        unsigned short hi, lo; split_bf16(v, hi, lo);
        size_t eo = ((size_t)b*PIXP + (h+1)*HP + (wp+1))*KK + t*DI + cc*64 + cl;
        Ah[eo] = hi; Al[eo] = lo;
      }
      __syncthreads();
    }
  }
}

// ---------------- K5d: MFMA GEMM (split-bf16, 3 mfma per K-step) ----------------
// grid.x = 448 M-frags (bh*4+mf), grid.y = 4 groups:
//  g&2 -> col half (0-79 / 80-159), g&1==0 -> offsets 0..4 (part0), g&1==1 -> offsets 5..8 + diff (part1,diffb)
__global__ __launch_bounds__(64) void k_gemm(const unsigned short* __restrict__ Ah,
                                             const unsigned short* __restrict__ Al,
                                             const unsigned short* __restrict__ Bp,
                                             const unsigned short* __restrict__ Bd,
                                             float* __restrict__ part0,
                                             float* __restrict__ part1,
                                             float* __restrict__ diffb){
  int lane = threadIdx.x;
  int mfrag = blockIdx.x;
  int g = blockIdx.y;
  int bh = mfrag >> 2, mf = mfrag & 3;
  int b = bh / HH, h = bh % HH;
  int wp = mf*16 + (lane & 15);
  int kg = lane >> 4;
  int nbase = (g & 2) ? 80 : 0;
  int col = nbase + (lane & 15);

  f4v acc[5], accd[5];
  #pragma unroll
  for (int nf = 0; nf < 5; ++nf){ acc[nf] = (f4v){0.f,0.f,0.f,0.f}; accd[nf] = (f4v){0.f,0.f,0.f,0.f}; }

  int offLo = (g & 1) ? 5 : 0;
  int offHi = (g & 1) ? 9 : 5;
  const unsigned short* BpLo = Bp + BPELEMS;

  for (int off = offLo; off < offHi; ++off){
    int dh = off / 3, dw = off % 3;
    size_t aBase = ((size_t)b*PIXP + (size_t)(h+dh)*HP + (wp+dw))*KK + kg*8;
    size_t bBase = ((size_t)(off*12)*NPAD + col)*32 + kg*8;
    #pragma unroll 2
    for (int ks = 0; ks < 12; ++ks){
      s8v ahi = *(const s8v*)(Ah + aBase + ks*32);
      s8v alo = *(const s8v*)(Al + aBase + ks*32);
      size_t be = bBase + (size_t)ks*NPAD*32;
      s8v bh_[5], bl_[5];
      #pragma unroll
      for (int nf = 0; nf < 5; ++nf){
        bh_[nf] = *(const s8v*)(Bp   + be + (size_t)nf*16*32);
        bl_[nf] = *(const s8v*)(BpLo + be + (size_t)nf*16*32);
      }
      #pragma unroll
      for (int nf = 0; nf < 5; ++nf)
        acc[nf] = __builtin_amdgcn_mfma_f32_16x16x32_bf16(ahi, bh_[nf], acc[nf], 0, 0, 0);
      #pragma unroll
      for (int nf = 0; nf < 5; ++nf)
        acc[nf] = __builtin_amdgcn_mfma_f32_16x16x32_bf16(alo, bh_[nf], acc[nf], 0, 0, 0);
      #pragma unroll
      for (int nf = 0; nf < 5; ++nf)
        acc[nf] = __builtin_amdgcn_mfma_f32_16x16x32_bf16(ahi, bl_[nf], acc[nf], 0, 0, 0);
    }
  }

  if (g & 1){
    const unsigned short* BdLo = Bd + BDELEMS;
    size_t aBase = ((size_t)b*PIXP + (size_t)(h+1)*HP + (wp+1))*KK + kg*8;
    size_t bBase = ((size_t)col)*32 + kg*8;
    #pragma unroll 2
    for (int ks = 0; ks < 12; ++ks){
      s8v ahi = *(const s8v*)(Ah + aBase + ks*32);
      s8v alo = *(const s8v*)(Al + aBase + ks*32);
      size_t be = bBase + (size_t)ks*NPAD*32;
      s8v bh_[5], bl_[5];
      #pragma unroll
      for (int nf = 0; nf < 5; ++nf){
        bh_[nf] = *(const s8v*)(Bd   + be + (size_t)nf*16*32);
        bl_[nf] = *(const s8v*)(BdLo + be + (size_t)nf*16*32);
      }
      #pragma unroll
      for (int nf = 0; nf < 5; ++nf)
        accd[nf] = __builtin_amdgcn_mfma_f32_16x16x32_bf16(ahi, bh_[nf], accd[nf], 0, 0, 0);
      #pragma unroll
      for (int nf = 0; nf < 5; ++nf)
        accd[nf] = __builtin_amdgcn_mfma_f32_16x16x32_bf16(alo, bh_[nf], accd[nf], 0, 0, 0);
      #pragma unroll
      for (int nf = 0; nf < 5; ++nf)
        accd[nf] = __builtin_amdgcn_mfma_f32_16x16x32_bf16(ahi, bl_[nf], accd[nf], 0, 0, 0);
    }
  }

  float* part = (g & 1) ? part1 : part0;
  int r0 = (lane >> 4) * 4;
  #pragma unroll
  for (int nf = 0; nf < 5; ++nf){
    int c2 = col + nf*16;
    #pragma unroll
    for (int i = 0; i < 4; ++i){
      int wpo = mf*16 + r0 + i;
      if (wpo < WW){
        size_t l = (size_t)b*LL + h*WW + wpo;
        part[l*NPAD + c2] = acc[nf][i];
        if (g & 1) diffb[l*NPAD + c2] = accd[nf][i];
      }
    }
  }
}

// ---------------- K5e: combine partials -> pooled[(b*4+k)*LL+l][o] ----------------
__global__ __launch_bounds__(256) void k_pool(const float* __restrict__ part0,
                                              const float* __restrict__ part1,
                                              const float* __restrict__ diffb,
                                              float* __restrict__ pooled){
  int idx = blockIdx.x*256 + threadIdx.x;
  if (idx >= NB*LL*NKO) return;
  int ko = idx % NKO; int l = idx / NKO;
  float lin = part0[(size_t)l*NPAD + ko] + part1[(size_t)l*NPAD + ko];
  float dv  = diffb[(size_t)l*NPAD + ko];
  float pv = lin + 0.5f*THETA_C*fabsf(dv);
  int b = l / LL, ll = l % LL;
  int k = ko / NCOUT, o = ko % NCOUT;
  pooled[(((size_t)b*4 + k)*LL + ll)*NCOUT + o] = pv;
}

// ---------------- K6a: scan pass A ----------------
__global__ __launch_bounds__(64) void k_scanA(const float* __restrict__ pooled,
                                              const float* __restrict__ xs,
                                              const float* __restrict__ dtw,
                                              const float* __restrict__ dtb,
                                              const float* __restrict__ alog,
                                              float* __restrict__ Pb,
                                              float* __restrict__ He){
  int d = blockIdx.z*64 + threadIdx.x;
  int bk = blockIdx.y;
  int c = blockIdx.x;
  int k = bk & 3;
  int kdix = k*DI + d;
  float A[NST], P[NST], hst[NST];
  #pragma unroll
  for (int n = 0; n < NST; ++n){ A[n] = -__expf(alog[kdix*NST + n]); P[n] = 1.f; hst[n] = 0.f; }
  float dwv[NDTR];
  #pragma unroll
  for (int r = 0; r < NDTR; ++r) dwv[r] = dtw[kdix*NDTR + r];
  float db = dtb[kdix];
  const float* prow = pooled + ((size_t)bk*LL + c*CLEN)*NCOUT;
  const float* urow = xs + ((size_t)bk*LL + c*CLEN)*DI + d;
  for (int p = 0; p < CLEN; ++p){
    float xr = db;
    #pragma unroll
    for (int r = 0; r < NDTR; ++r) xr += prow[r]*dwv[r];
    float delta = softplusf(xr);
    float u = urow[0];
    float du = delta * u;
    #pragma unroll
    for (int n = 0; n < NST; ++n){
      float dA = __expf(delta * A[n]);
      P[n]  *= dA;
      hst[n] = dA*hst[n] + du*prow[6+n];
    }
    prow += NCOUT; urow += DI;
  }
  float* pp = Pb + (((size_t)bk*NCH + c)*DI + d)*NST;
  float* hp = He + (((size_t)bk*NCH + c)*DI + d)*NST;
  #pragma unroll
  for (int n = 0; n < NST; ++n){ pp[n] = P[n]; hp[n] = hst[n]; }
}

// ---------------- K6b: cross-chunk prefix ----------------
__global__ __launch_bounds__(256) void k_scanB(const float* __restrict__ Pb,
                                               const float* __restrict__ He,
                                               float* __restrict__ H0){
  int t = blockIdx.x*256 + threadIdx.x;
  if (t >= NB*4*DI*NST) return;
  int bk = t / (DI*NST);
  int dn = t % (DI*NST);
  float hcur = 0.f;
  for (int c = 0; c < NCH; ++c){
    size_t off = ((size_t)bk*NCH + c)*DI*NST + dn;
    H0[off] = hcur;
    hcur = Pb[off]*hcur + He[off];
  }
}

// ---------------- K6c: scan pass C ----------------
__global__ __launch_bounds__(64) void k_scanC(const float* __restrict__ pooled,
                                              const float* __restrict__ xs,
                                              const float* __restrict__ dtw,
                                              const float* __restrict__ dtb,
                                              const float* __restrict__ alog,
                                              const float* __restrict__ Dsv,
                                              const float* __restrict__ H0,
                                              float* __restrict__ oy){
  int d = blockIdx.z*64 + threadIdx.x;
  int bk = blockIdx.y;
  int c = blockIdx.x;
  int k = bk & 3;
  int kdix = k*DI + d;
  float A[NST], hst[NST];
  const float* h0p = H0 + (((size_t)bk*NCH + c)*DI + d)*NST;
  #pragma unroll
  for (int n = 0; n < NST; ++n){ A[n] = -__expf(alog[kdix*NST + n]); hst[n] = h0p[n]; }
  float dwv[NDTR];
  #pragma unroll
  for (int r = 0; r < NDTR; ++r) dwv[r] = dtw[kdix*NDTR + r];
  float db = dtb[kdix];
  float Dv = Dsv[kdix];
  const float* prow = pooled + ((size_t)bk*LL + c*CLEN)*NCOUT;
  const float* urow = xs + ((size_t)bk*LL + c*CLEN)*DI + d;
  float* orow = oy + ((size_t)bk*LL + c*CLEN)*DI + d;
  for (int p = 0; p < CLEN; ++p){
    float xr = db;
    #pragma unroll
    for (int r = 0; r < NDTR; ++r) xr += prow[r]*dwv[r];
    float delta = softplusf(xr);
    float u = urow[0];
    float du = delta * u;
    float y = 0.f;
    #pragma unroll
    for (int n = 0; n < NST; ++n){
      float dA = __expf(delta * A[n]);
      hst[n] = dA*hst[n] + du*prow[6+n];
      y += hst[n]*prow[22+n];
    }
    orow[0] = y + Dv*u;
    prow += NCOUT; urow += DI; orow += DI;
  }
}

// ---------------- K7: merge + LN + gate + out_proj ----------------
__global__ __launch_bounds__(192) void k_out(const float* __restrict__ oy,
                                             const float* __restrict__ xz,
                                             const float* __restrict__ lng,
                                             const float* __restrict__ lnb,
                                             const float* __restrict__ opw,
                                             float* __restrict__ out){
  __shared__ float ygs[DI];
  __shared__ float redS[3], redQ[3];
  int bl = blockIdx.x; int b = bl / LL; int l = bl % LL;
  int d = threadIdx.x;
  int h = l / WW, wp = l % WW;
  int p2 = wp*HH + h;
  size_t b4 = (size_t)b*4;
  float y = oy[((b4+0)*LL + l)*DI + d]
          + oy[((b4+2)*LL + (LL-1-l))*DI + d]
          + oy[((b4+1)*LL + p2)*DI + d]
          + oy[((b4+3)*LL + (LL-1-p2))*DI + d];
  float s = y, q = y*y;
  #pragma unroll
  for (int m = 1; m < 64; m <<= 1){ s += __shfl_xor(s, m); q += __shfl_xor(q, m); }
  int wv = d >> 6;
  if ((d & 63) == 0){ redS[wv] = s; redQ[wv] = q; }
  __syncthreads();
  float S = redS[0]+redS[1]+redS[2];
  float Q = redQ[0]+redQ[1]+redQ[2];
  float mu = S * (1.f/DI);
  float var = Q * (1.f/DI) - mu*mu;
  float yn = (y - mu) * rsqrtf(var + 1e-5f) * lng[d] + lnb[d];
  float zv = xz[((size_t)b*384 + 192 + d)*LL + l];
  ygs[d] = yn * siluf(zv);
  __syncthreads();
  if (d < 96){
    const float* wr = opw + (size_t)d*DI;
    float acc = 0.f;
    #pragma unroll 4
    for (int dd = 0; dd < DI; ++dd) acc += ygs[dd]*wr[dd];
    out[(size_t)bl*96 + d] = acc;
  }
}

extern "C" void kernel_launch(void* const* d_in, const int* in_sizes, int n_in,
                              void* d_out, int out_size, void* d_ws, size_t ws_size,
                              hipStream_t stream){
  const float* x    = (const float*)d_in[0];
  const float* xt   = (const float*)d_in[1];
  const float* ipw  = (const float*)d_in[2];
  const float* c2w  = (const float*)d_in[3];
  const float* c2b  = (const float*)d_in[4];
  const float* cxw  = (const float*)d_in[5];
  const float* cxb  = (const float*)d_in[6];
  const float* xpw  = (const float*)d_in[7];
  const float* dtw  = (const float*)d_in[8];
  const float* dtb  = (const float*)d_in[9];
  const float* alog = (const float*)d_in[10];
  const float* Dsv  = (const float*)d_in[11];
  const float* lng  = (const float*)d_in[12];
  const float* lnb  = (const float*)d_in[13];
  const float* opw  = (const float*)d_in[14];
  float* out = (float*)d_out;

  float* ws   = (float*)d_ws;
  float* xz   = ws;                                   // 2,408,448
  float* xc   = xz  + (size_t)NB*384*LL;              // 1,204,224
  float* xtc  = xc  + (size_t)NB*DI*LL;               // 1,204,224
  float* xs   = xtc + (size_t)NB*DI*LL;               // 4,816,896
  float* pool = xs  + (size_t)NB*4*LL*DI;             // 953,344
  float* kd   = pool+ (size_t)NB*4*LL*NCOUT;          // 29,184
  // U1: union of {A/B packs} (used up to k_gemm) and {Pb,He,H0} (used after)
  float* U1   = kd  + (size_t)NKO*DI;                 // 4,718,592 floats
  float* Pb   = U1;
  float* He   = Pb  + (size_t)NB*4*NCH*DI*NST;
  float* H0   = He  + (size_t)NB*4*NCH*DI*NST;
  unsigned short* Ahi = (unsigned short*)U1;
  unsigned short* Alo = Ahi + AELEMS;
  unsigned short* Bp  = Alo + AELEMS;
  unsigned short* Bd  = Bp + 2*BPELEMS;
  // U2: union of {part0,part1,diffb} (pre-k_pool) and {oy} (post)
  float* U2   = U1 + 3*(size_t)NB*4*NCH*DI*NST;       // 4,816,896 floats
  float* oy   = U2;
  float* part0 = U2;
  float* part1 = U2 + (size_t)NB*LL*NPAD;
  float* diffb = U2 + 2*(size_t)NB*LL*NPAD;

  // zero padded-A field (borders must be 0)
  hipMemsetAsync((void*)Ahi, 0, 2*AELEMS*sizeof(unsigned short), stream);

  k_inproj<<<NB*LL/8, 256, 0, stream>>>(x, ipw, xz);
  int n1 = NB*DI*LL;
  k_conv_xc<<<(n1+255)/256, 256, 0, stream>>>(xz, c2w, c2b, xc);
  k_conv_xt<<<(n1+255)/256, 256, 0, stream>>>(xt, cxw, cxb, xtc);
  k_xs<<<(n1+255)/256, 256, 0, stream>>>(xc, xtc, xs);
  k_kd<<<(NKO*DI+255)/256, 256, 0, stream>>>(xpw, kd);
  k_wpack<<<(BPELEMS+BDELEMS+255)/256, 256, 0, stream>>>(xpw, kd, Bp, Bd);
  k_apack<<<dim3(HH, NB), 256, 0, stream>>>(xc, xtc, Ahi, Alo);
  k_gemm<<<dim3(448, 4), 64, 0, stream>>>(Ahi, Alo, Bp, Bd, part0, part1, diffb);
  k_pool<<<(NB*LL*NKO+255)/256, 256, 0, stream>>>(part0, part1, diffb, pool);
  k_scanA<<<dim3(NCH, NB*4, 3), 64, 0, stream>>>(pool, xs, dtw, dtb, alog, Pb, He);
  k_scanB<<<(NB*4*DI*NST+255)/256, 256, 0, stream>>>(Pb, He, H0);
  k_scanC<<<dim3(NCH, NB*4, 3), 64, 0, stream>>>(pool, xs, dtw, dtb, alog, Dsv, H0, oy);
  k_out<<<NB*LL, 192, 0, stream>>>(oy, xz, lng, lnb, opw, out);
}

// Round 3
// 388.293 us; speedup vs baseline: 1.8002x; 1.2696x over previous
//
#include <hip/hip_runtime.h>
#include <math.h>

#define LL 3136
#define HH 56
#define WW 56
#define DI 192
#define NB 2
#define NCOUT 38
#define NKO 152
#define NST 16
#define NDTR 6
#define NCH 64     // number of scan chunks
#define CLEN 49    // LL / NCH
#define THETA_C 0.6f

// padded A field: 58x58 pixels, K=384 (t*192+c) contiguous
#define HP 58
#define PIXP (HP*HP)          // 3364
#define KK 384
#define NPAD 160              // padded N for GEMM cols
#define AELEMS ((size_t)NB*PIXP*KK)       // 2,583,552 bf16 per array
#define BPELEMS (9*12*NPAD*32)            // 552,960 per (hi|lo)
#define BDELEMS (12*NPAD*32)              // 61,440 per (hi|lo)
#define PSZ ((size_t)NB*LL*NPAD)          // 1,003,520 floats per partial

typedef short s8v __attribute__((ext_vector_type(8)));
typedef float f4v __attribute__((ext_vector_type(4)));

__device__ __forceinline__ float siluf(float x){ return x * (1.0f / (1.0f + __expf(-x))); }
__device__ __forceinline__ float softplusf(float x){ return (x > 20.0f) ? x : log1pf(__expf(x)); }
__device__ __forceinline__ void split_bf16(float v, unsigned short& hi, unsigned short& lo){
  unsigned bits = __float_as_uint(v);
  hi = (unsigned short)(bits >> 16);
  float hif = __uint_as_float(((unsigned)hi) << 16);
  float lof = v - hif;
  lo = (unsigned short)(__float_as_uint(lof) >> 16);
}

// ---------------- K1: in_proj GEMM  xz[b][e][l] = sum_c x[b,l,c] * w[e,c] ----------------
__global__ __launch_bounds__(512) void k_inproj(const float* __restrict__ x,
                                                const float* __restrict__ w,
                                                float* __restrict__ xz){
  __shared__ float xsh[16][100];
  int bl0 = blockIdx.x * 16;
  int tid = threadIdx.x;
  for (int i = tid; i < 16*96; i += 512){
    xsh[i/96][i%96] = x[(size_t)(bl0 + i/96)*96 + (i%96)];
  }
  __syncthreads();
  int lt = tid & 15, e0 = tid >> 4;   // e0 0..31
  int bl = bl0 + lt;
  int b = bl / LL, l = bl % LL;
  for (int j = 0; j < 12; ++j){
    int e = e0 + 32*j;
    const float* wr = w + e*96;
    float acc = 0.f;
    #pragma unroll
    for (int c = 0; c < 96; c += 4){
      acc += xsh[lt][c]*wr[c] + xsh[lt][c+1]*wr[c+1]
           + xsh[lt][c+2]*wr[c+2] + xsh[lt][c+3]*wr[c+3];
    }
    xz[((size_t)b*384 + e)*LL + l] = acc;
  }
}

// ---------------- K1b: transpose xt (NHWC -> [b][c][l]) ----------------
__global__ __launch_bounds__(256) void k_txt(const float* __restrict__ xt,
                                             float* __restrict__ xtT){
  __shared__ float tile[16][97];
  int l0 = blockIdx.x * 16; int b = blockIdx.y;
  for (int i = threadIdx.x; i < 16*96; i += 256){
    int ll = i / 96, c = i % 96;
    tile[ll][c] = xt[((size_t)b*LL + l0 + ll)*96 + c];
  }
  __syncthreads();
  for (int o = threadIdx.x; o < 96*16; o += 256){
    int c = o >> 4, ll = o & 15;
    xtT[((size_t)b*96 + c)*LL + l0 + ll] = tile[ll][c];
  }
}

// ---------------- K2: depthwise conv 3x3 + bias + SiLU ----------------
__global__ __launch_bounds__(256) void k_conv_xc(const float* __restrict__ xz,
                                                 const float* __restrict__ cw,
                                                 const float* __restrict__ cb,
                                                 float* __restrict__ xc){
  int idx = blockIdx.x*256 + threadIdx.x;
  if (idx >= NB*DI*LL) return;
  int l = idx % LL; int d = (idx / LL) % DI; int b = idx / (DI*LL);
  int h = l / WW, wp = l % WW;
  const float* src = xz + ((size_t)b*384 + d)*LL;
  const float* wk = cw + d*9;
  float acc = cb[d];
  #pragma unroll
  for (int dh = 0; dh < 3; ++dh){
    int hh = h + dh - 1; if (hh < 0 || hh >= HH) continue;
    const float* row = src + hh*WW;
    #pragma unroll
    for (int dw = 0; dw < 3; ++dw){
      int wq = wp + dw - 1; if (wq < 0 || wq >= WW) continue;
      acc += wk[dh*3+dw] * row[wq];
    }
  }
  xc[((size_t)b*DI + d)*LL + l] = siluf(acc);
}

// ---------------- K3: grouped conv on xtT (rows coalesced) ----------------
__global__ __launch_bounds__(256) void k_conv_xt(const float* __restrict__ xtT,
                                                 const float* __restrict__ cw,
                                                 const float* __restrict__ cb,
                                                 float* __restrict__ xtc){
  int idx = blockIdx.x*256 + threadIdx.x;
  if (idx >= NB*DI*LL) return;
  int l = idx % LL; int d = (idx / LL) % DI; int b = idx / (DI*LL);
  int h = l / WW, wp = l % WW;
  int c = d >> 1;
  const float* src = xtT + ((size_t)b*96 + c)*LL;
  const float* wk = cw + d*9;
  float acc = cb[d];
  #pragma unroll
  for (int dh = 0; dh < 3; ++dh){
    int hh = h + dh - 1; if (hh < 0 || hh >= HH) continue;
    const float* row = src + hh*WW;
    #pragma unroll
    for (int dw = 0; dw < 3; ++dw){
      int wq = wp + dw - 1; if (wq < 0 || wq >= WW) continue;
      acc += wk[dh*3+dw] * row[wq];
    }
  }
  xtc[((size_t)b*DI + d)*LL + l] = siluf(acc);
}

// ---------------- K4: pools -> 2 directional base sequences xs[b][dir][l][d] ----------------
// dir0 (row-pool, transposed raster pos=wp*56+h), dir1 (col-pool, pos=h*56+wp).
// k=1,3 are within-row flips handled by the scan's index math.
__global__ __launch_bounds__(256) void k_xs(const float* __restrict__ xc,
                                            const float* __restrict__ xtc,
                                            float* __restrict__ xs){
  __shared__ float T[4][32][57];
  int h = blockIdx.x, b = blockIdx.y, dt = blockIdx.z;  // dt 0..5
  int d0 = dt*32;
  int i0 = (h >> 1) * 2;
  const float* rsrc = (h & 1) ? xtc : xc;
  for (int i = threadIdx.x; i < 4*32*56; i += 256){
    int pl = i / (32*56); int r = i % (32*56); int dl = r / 56; int w = r % 56;
    const float* s; int row;
    if (pl == 0){ s = xc;  row = h; }
    else if (pl == 1){ s = xtc; row = h; }
    else if (pl == 2){ s = rsrc; row = i0; }
    else { s = rsrc; row = i0 + 1; }
    T[pl][dl][w] = s[((size_t)b*DI + d0 + dl)*LL + row*WW + w];
  }
  __syncthreads();
  for (int o = threadIdx.x; o < 2*56*32; o += 256){
    int out = o / (56*32); int r = o % (56*32); int wp = r / 32; int dl = r & 31;
    if (out == 1){
      int s = wp & 1; int w0 = (wp >> 1) * 2;
      float a0 = T[s][dl][w0], a1 = T[s][dl][w0+1];
      float ic = 0.5f*(a0+a1) + fmaxf(a0,a1);
      xs[(((size_t)b*2 + 1)*LL + h*WW + wp)*DI + d0 + dl] = ic;
    } else {
      float r0 = T[2][dl][wp], r1 = T[3][dl][wp];
      float ir = 0.5f*(r0+r1) + fmaxf(r0,r1);
      xs[(((size_t)b*2 + 0)*LL + wp*HH + h)*DI + d0 + dl] = ir;
    }
  }
}

// ---------------- K5a: kernel_diff[ko][c] ----------------
__global__ __launch_bounds__(256) void k_kd(const float* __restrict__ xpw, float* __restrict__ kd){
  int idx = blockIdx.x*256 + threadIdx.x;
  if (idx >= NKO*DI) return;
  const float* p = xpw + (size_t)idx*18;
  float s = 0.f;
  #pragma unroll
  for (int i = 0; i < 18; ++i) s += p[i];
  kd[idx] = s;
}

// ---------------- K5b: pack weights (fragment layout, hi/lo bf16) ----------------
__global__ __launch_bounds__(256) void k_wpack(const float* __restrict__ xpw,
                                               const float* __restrict__ kd,
                                               unsigned short* __restrict__ Bp,
                                               unsigned short* __restrict__ Bd){
  int idx = blockIdx.x*256 + threadIdx.x;
  if (idx < BPELEMS){
    int q = idx & 31; int n = (idx >> 5) % NPAD; int oks = idx / (NPAD*32);
    int ks = oks % 12, off = oks / 12;
    int k = ks*32 + q;
    int t = k / DI, c = k % DI;
    float v = 0.f;
    if (n < NKO){
      float w = xpw[((size_t)(n*DI + c)*2 + t)*9 + off];
      v = 2.f*w;
      if (off == 4) v -= THETA_C * kd[n*DI + c];
    }
    unsigned short hi, lo; split_bf16(v, hi, lo);
    Bp[idx] = hi; Bp[BPELEMS + idx] = lo;
  } else {
    int id2 = idx - BPELEMS;
    if (id2 >= BDELEMS) return;
    int q = id2 & 31; int n = (id2 >> 5) % NPAD; int ks = id2 / (NPAD*32);
    int k = ks*32 + q;
    int t = k / DI, c = k % DI;
    float v = 0.f;
    if (n < NKO){
      float kv = kd[n*DI + c];
      v = (t == 0) ? kv : -kv;
    }
    unsigned short hi, lo; split_bf16(v, hi, lo);
    Bd[id2] = hi; Bd[BDELEMS + id2] = lo;
  }
}

// ---------------- K5c: pack A (padded 58x58, K contiguous), hi/lo bf16 ----------------
__global__ __launch_bounds__(256) void k_apack(const float* __restrict__ xc,
                                               const float* __restrict__ xtc,
                                               unsigned short* __restrict__ Ah,
                                               unsigned short* __restrict__ Al){
  __shared__ float tile[64*57];
  int h = blockIdx.x, b = blockIdx.y, z = blockIdx.z;
  int t = z / 3, cc = z % 3;
  const float* src = (t ? xtc : xc) + (size_t)b*DI*LL;
  for (int i = threadIdx.x; i < 64*56; i += 256){
    int ci = i / 56, wpx = i % 56;
    tile[ci*57 + wpx] = src[(size_t)(cc*64 + ci)*LL + h*WW + wpx];
  }
  __syncthreads();
  int cl = threadIdx.x & 63, wv = threadIdx.x >> 6;
  for (int wp = wv; wp < WW; wp += 4){
    float v = tile[cl*57 + wp];
    unsigned short hi, lo; split_bf16(v, hi, lo);
    size_t eo = ((size_t)b*PIXP + (size_t)(h+1)*HP + (wp+1))*KK + t*DI + cc*64 + cl;
    Ah[eo] = hi; Al[eo] = lo;
  }
}

// ---------------- K5d: MFMA GEMM, 14-way split for occupancy ----------------
// grid (448, 14): g = ch(2) x q(7). q<6: og=q%3 (offsets 3og..3og+2), kh=q/3 (ks 6kh..6kh+5) -> parts[q]
//                 q==6: diff (center tap, Bd, all 12 ks) -> parts[6]
__global__ __launch_bounds__(64) void k_gemm(const unsigned short* __restrict__ Ah,
                                             const unsigned short* __restrict__ Al,
                                             const unsigned short* __restrict__ Bp,
                                             const unsigned short* __restrict__ Bd,
                                             float* __restrict__ parts){
  int lane = threadIdx.x;
  int mfrag = blockIdx.x;
  int g = blockIdx.y;
  int ch = g & 1, q = g >> 1;
  int bh = mfrag >> 2, mf = mfrag & 3;
  int b = bh / HH, h = bh % HH;
  int wp = mf*16 + (lane & 15);
  int kg = lane >> 4;
  int col = ch*80 + (lane & 15);

  f4v acc[5];
  #pragma unroll
  for (int nf = 0; nf < 5; ++nf) acc[nf] = (f4v){0.f,0.f,0.f,0.f};

  if (q < 6){
    const unsigned short* BpLo = Bp + BPELEMS;
    int og = q % 3, kh = q / 3;
    for (int off = 3*og; off < 3*og + 3; ++off){
      int dh = off / 3, dw = off % 3;
      size_t aB0 = ((size_t)b*PIXP + (size_t)(h+dh)*HP + (wp+dw))*KK + kg*8;
      size_t bB0 = ((size_t)(off*12)*NPAD + col)*32 + kg*8;
      #pragma unroll 2
      for (int ks = 6*kh; ks < 6*kh + 6; ++ks){
        s8v ahi = *(const s8v*)(Ah + aB0 + ks*32);
        s8v alo = *(const s8v*)(Al + aB0 + ks*32);
        size_t be = bB0 + (size_t)ks*NPAD*32;
        s8v bhv[5], blv[5];
        #pragma unroll
        for (int nf = 0; nf < 5; ++nf){
          bhv[nf] = *(const s8v*)(Bp   + be + (size_t)nf*16*32);
          blv[nf] = *(const s8v*)(BpLo + be + (size_t)nf*16*32);
        }
        #pragma unroll
        for (int nf = 0; nf < 5; ++nf)
          acc[nf] = __builtin_amdgcn_mfma_f32_16x16x32_bf16(ahi, bhv[nf], acc[nf], 0, 0, 0);
        #pragma unroll
        for (int nf = 0; nf < 5; ++nf)
          acc[nf] = __builtin_amdgcn_mfma_f32_16x16x32_bf16(alo, bhv[nf], acc[nf], 0, 0, 0);
        #pragma unroll
        for (int nf = 0; nf < 5; ++nf)
          acc[nf] = __builtin_amdgcn_mfma_f32_16x16x32_bf16(ahi, blv[nf], acc[nf], 0, 0, 0);
      }
    }
  } else {
    const unsigned short* BdLo = Bd + BDELEMS;
    size_t aB0 = ((size_t)b*PIXP + (size_t)(h+1)*HP + (wp+1))*KK + kg*8;
    size_t bB0 = ((size_t)col)*32 + kg*8;
    #pragma unroll 2
    for (int ks = 0; ks < 12; ++ks){
      s8v ahi = *(const s8v*)(Ah + aB0 + ks*32);
      s8v alo = *(const s8v*)(Al + aB0 + ks*32);
      size_t be = bB0 + (size_t)ks*NPAD*32;
      s8v bhv[5], blv[5];
      #pragma unroll
      for (int nf = 0; nf < 5; ++nf){
        bhv[nf] = *(const s8v*)(Bd   + be + (size_t)nf*16*32);
        blv[nf] = *(const s8v*)(BdLo + be + (size_t)nf*16*32);
      }
      #pragma unroll
      for (int nf = 0; nf < 5; ++nf)
        acc[nf] = __builtin_amdgcn_mfma_f32_16x16x32_bf16(ahi, bhv[nf], acc[nf], 0, 0, 0);
      #pragma unroll
      for (int nf = 0; nf < 5; ++nf)
        acc[nf] = __builtin_amdgcn_mfma_f32_16x16x32_bf16(alo, bhv[nf], acc[nf], 0, 0, 0);
      #pragma unroll
      for (int nf = 0; nf < 5; ++nf)
        acc[nf] = __builtin_amdgcn_mfma_f32_16x16x32_bf16(ahi, blv[nf], acc[nf], 0, 0, 0);
    }
  }

  float* part = parts + (size_t)q*PSZ;
  int r0 = kg * 4;
  #pragma unroll
  for (int nf = 0; nf < 5; ++nf){
    int c2 = col + nf*16;
    #pragma unroll
    for (int i = 0; i < 4; ++i){
      int wpo = mf*16 + r0 + i;
      if (wpo < WW)
        part[((size_t)b*LL + h*WW + wpo)*NPAD + c2] = acc[nf][i];
    }
  }
}

// ---------------- K5e: combine partials -> pooled ----------------
__global__ __launch_bounds__(256) void k_pool(const float* __restrict__ parts,
                                              float* __restrict__ pooled){
  int idx = blockIdx.x*256 + threadIdx.x;
  if (idx >= NB*LL*NKO) return;
  int ko = idx % NKO; int l = idx / NKO;
  size_t e = (size_t)l*NPAD + ko;
  float lin = 0.f;
  #pragma unroll
  for (int q = 0; q < 6; ++q) lin += parts[q*PSZ + e];
  float dv = parts[6*PSZ + e];
  float pv = lin + 0.5f*THETA_C*fabsf(dv);
  int b = l / LL, ll = l % LL;
  int k = ko / NCOUT, o = ko % NCOUT;
  pooled[(((size_t)b*4 + k)*LL + ll)*NCOUT + o] = pv;
}

// ---------------- K6a: scan pass A ----------------
__global__ __launch_bounds__(64) void k_scanA(const float* __restrict__ pooled,
                                              const float* __restrict__ xs,
                                              const float* __restrict__ dtw,
                                              const float* __restrict__ dtb,
                                              const float* __restrict__ alog,
                                              float* __restrict__ Pb,
                                              float* __restrict__ He){
  int d = blockIdx.z*64 + threadIdx.x;
  int bk = blockIdx.y;
  int c = blockIdx.x;
  int k = bk & 3, b = bk >> 2;
  int kdix = k*DI + d;
  int dir = (k >> 1) & 1;
  int flip = k & 1;
  float A[NST], P[NST], hst[NST];
  #pragma unroll
  for (int n = 0; n < NST; ++n){ A[n] = -__expf(alog[kdix*NST + n]); P[n] = 1.f; hst[n] = 0.f; }
  float dwv[NDTR];
  #pragma unroll
  for (int r = 0; r < NDTR; ++r) dwv[r] = dtw[kdix*NDTR + r];
  float db = dtb[kdix];
  const float* prow = pooled + ((size_t)bk*LL + c*CLEN)*NCOUT;
  const float* xsd = xs + ((size_t)(b*2 + dir)*LL)*DI + d;
  int pos = c*CLEN;
  int wp = pos % 56, rowb = pos - wp;
  for (int p = 0; p < CLEN; ++p){
    float xr = db;
    #pragma unroll
    for (int r = 0; r < NDTR; ++r) xr += prow[r]*dwv[r];
    float delta = softplusf(xr);
    int upos = flip ? (rowb + 55 - wp) : pos;
    float u = xsd[(size_t)upos*DI];
    float du = delta * u;
    #pragma unroll
    for (int n = 0; n < NST; ++n){
      float dA = __expf(delta * A[n]);
      P[n]  *= dA;
      hst[n] = dA*hst[n] + du*prow[6+n];
    }
    prow += NCOUT;
    ++pos; ++wp; if (wp == 56){ wp = 0; rowb = pos; }
  }
  float* pp = Pb + (((size_t)bk*NCH + c)*DI + d)*NST;
  float* hp = He + (((size_t)bk*NCH + c)*DI + d)*NST;
  #pragma unroll
  for (int n = 0; n < NST; ++n){ pp[n] = P[n]; hp[n] = hst[n]; }
}

// ---------------- K6b: cross-chunk prefix ----------------
__global__ __launch_bounds__(256) void k_scanB(const float* __restrict__ Pb,
                                               const float* __restrict__ He,
                                               float* __restrict__ H0){
  int t = blockIdx.x*256 + threadIdx.x;
  if (t >= NB*4*DI*NST) return;
  int bk = t / (DI*NST);
  int dn = t % (DI*NST);
  float hcur = 0.f;
  for (int c = 0; c < NCH; ++c){
    size_t off = ((size_t)bk*NCH + c)*DI*NST + dn;
    H0[off] = hcur;
    hcur = Pb[off]*hcur + He[off];
  }
}

// ---------------- K6c: scan pass C ----------------
__global__ __launch_bounds__(64) void k_scanC(const float* __restrict__ pooled,
                                              const float* __restrict__ xs,
                                              const float* __restrict__ dtw,
                                              const float* __restrict__ dtb,
                                              const float* __restrict__ alog,
                                              const float* __restrict__ Dsv,
                                              const float* __restrict__ H0,
                                              float* __restrict__ oy){
  int d = blockIdx.z*64 + threadIdx.x;
  int bk = blockIdx.y;
  int c = blockIdx.x;
  int k = bk & 3, b = bk >> 2;
  int kdix = k*DI + d;
  int dir = (k >> 1) & 1;
  int flip = k & 1;
  float A[NST], hst[NST];
  const float* h0p = H0 + (((size_t)bk*NCH + c)*DI + d)*NST;
  #pragma unroll
  for (int n = 0; n < NST; ++n){ A[n] = -__expf(alog[kdix*NST + n]); hst[n] = h0p[n]; }
  float dwv[NDTR];
  #pragma unroll
  for (int r = 0; r < NDTR; ++r) dwv[r] = dtw[kdix*NDTR + r];
  float db = dtb[kdix];
  float Dv = Dsv[kdix];
  const float* prow = pooled + ((size_t)bk*LL + c*CLEN)*NCOUT;
  const float* xsd = xs + ((size_t)(b*2 + dir)*LL)*DI + d;
  float* orow = oy + ((size_t)bk*LL + c*CLEN)*DI + d;
  int pos = c*CLEN;
  int wp = pos % 56, rowb = pos - wp;
  for (int p = 0; p < CLEN; ++p){
    float xr = db;
    #pragma unroll
    for (int r = 0; r < NDTR; ++r) xr += prow[r]*dwv[r];
    float delta = softplusf(xr);
    int upos = flip ? (rowb + 55 - wp) : pos;
    float u = xsd[(size_t)upos*DI];
    float du = delta * u;
    float y = 0.f;
    #pragma unroll
    for (int n = 0; n < NST; ++n){
      float dA = __expf(delta * A[n]);
      hst[n] = dA*hst[n] + du*prow[6+n];
      y += hst[n]*prow[22+n];
    }
    orow[0] = y + Dv*u;
    prow += NCOUT; orow += DI;
    ++pos; ++wp; if (wp == 56){ wp = 0; rowb = pos; }
  }
}

// ---------------- K7: merge + LN + gate + out_proj ----------------
__global__ __launch_bounds__(192) void k_out(const float* __restrict__ oy,
                                             const float* __restrict__ xz,
                                             const float* __restrict__ lng,
                                             const float* __restrict__ lnb,
                                             const float* __restrict__ opw,
                                             float* __restrict__ out){
  __shared__ float ygs[DI];
  __shared__ float redS[3], redQ[3];
  int bl = blockIdx.x; int b = bl / LL; int l = bl % LL;
  int d = threadIdx.x;
  int h = l / WW, wp = l % WW;
  int p2 = wp*HH + h;
  size_t b4 = (size_t)b*4;
  float y = oy[((b4+0)*LL + l)*DI + d]
          + oy[((b4+2)*LL + (LL-1-l))*DI + d]
          + oy[((b4+1)*LL + p2)*DI + d]
          + oy[((b4+3)*LL + (LL-1-p2))*DI + d];
  float s = y, q = y*y;
  #pragma unroll
  for (int m = 1; m < 64; m <<= 1){ s += __shfl_xor(s, m); q += __shfl_xor(q, m); }
  int wv = d >> 6;
  if ((d & 63) == 0){ redS[wv] = s; redQ[wv] = q; }
  __syncthreads();
  float S = redS[0]+redS[1]+redS[2];
  float Q = redQ[0]+redQ[1]+redQ[2];
  float mu = S * (1.f/DI);
  float var = Q * (1.f/DI) - mu*mu;
  float yn = (y - mu) * rsqrtf(var + 1e-5f) * lng[d] + lnb[d];
  float zv = xz[((size_t)b*384 + 192 + d)*LL + l];
  ygs[d] = yn * siluf(zv);
  __syncthreads();
  if (d < 96){
    const float* wr = opw + (size_t)d*DI;
    float acc = 0.f;
    #pragma unroll 4
    for (int dd = 0; dd < DI; ++dd) acc += ygs[dd]*wr[dd];
    out[(size_t)bl*96 + d] = acc;
  }
}

extern "C" void kernel_launch(void* const* d_in, const int* in_sizes, int n_in,
                              void* d_out, int out_size, void* d_ws, size_t ws_size,
                              hipStream_t stream){
  const float* x    = (const float*)d_in[0];
  const float* xt   = (const float*)d_in[1];
  const float* ipw  = (const float*)d_in[2];
  const float* c2w  = (const float*)d_in[3];
  const float* c2b  = (const float*)d_in[4];
  const float* cxw  = (const float*)d_in[5];
  const float* cxb  = (const float*)d_in[6];
  const float* xpw  = (const float*)d_in[7];
  const float* dtw  = (const float*)d_in[8];
  const float* dtb  = (const float*)d_in[9];
  const float* alog = (const float*)d_in[10];
  const float* Dsv  = (const float*)d_in[11];
  const float* lng  = (const float*)d_in[12];
  const float* lnb  = (const float*)d_in[13];
  const float* opw  = (const float*)d_in[14];
  float* out = (float*)d_out;

  float* ws   = (float*)d_ws;
  float* xz   = ws;                                   // 2,408,448
  float* xc   = xz  + (size_t)NB*384*LL;              // 1,204,224
  float* xtc  = xc  + (size_t)NB*DI*LL;               // 1,204,224
  float* xs   = xtc + (size_t)NB*DI*LL;               // 2,408,448 (2 dirs)
  float* pool = xs  + (size_t)NB*2*LL*DI;             // 953,344
  float* kd   = pool+ (size_t)NB*4*LL*NCOUT;          // 29,184
  // U1: union of {Ah,Al,Bp,Bd packs} and {Pb,He,H0}
  float* U1   = kd  + (size_t)NKO*DI;                 // 4,718,592
  float* Pb   = U1;
  float* He   = Pb  + (size_t)NB*4*NCH*DI*NST;
  float* H0   = He  + (size_t)NB*4*NCH*DI*NST;
  unsigned short* Ahi = (unsigned short*)U1;
  unsigned short* Alo = Ahi + AELEMS;
  unsigned short* Bp  = Alo + AELEMS;
  unsigned short* Bd  = Bp + 2*BPELEMS;
  // U2: union of {parts[7]} , {oy} , {xtT in slot 6}
  float* U2   = U1 + 3*(size_t)NB*4*NCH*DI*NST;       // 7,024,640
  float* parts = U2;
  float* oy    = U2;
  float* xtT   = U2 + 6*PSZ;

  hipMemsetAsync((void*)Ahi, 0, 2*AELEMS*sizeof(unsigned short), stream);

  k_inproj<<<NB*LL/16, 512, 0, stream>>>(x, ipw, xz);
  k_txt<<<dim3(LL/16, NB), 256, 0, stream>>>(xt, xtT);
  int n1 = NB*DI*LL;
  k_conv_xc<<<(n1+255)/256, 256, 0, stream>>>(xz, c2w, c2b, xc);
  k_conv_xt<<<(n1+255)/256, 256, 0, stream>>>(xtT, cxw, cxb, xtc);
  k_xs<<<dim3(HH, NB, 6), 256, 0, stream>>>(xc, xtc, xs);
  k_kd<<<(NKO*DI+255)/256, 256, 0, stream>>>(xpw, kd);
  k_wpack<<<(BPELEMS+BDELEMS+255)/256, 256, 0, stream>>>(xpw, kd, Bp, Bd);
  k_apack<<<dim3(HH, NB, 6), 256, 0, stream>>>(xc, xtc, Ahi, Alo);
  k_gemm<<<dim3(448, 14), 64, 0, stream>>>(Ahi, Alo, Bp, Bd, parts);
  k_pool<<<(NB*LL*NKO+255)/256, 256, 0, stream>>>(parts, pool);
  k_scanA<<<dim3(NCH, NB*4, 3), 64, 0, stream>>>(pool, xs, dtw, dtb, alog, Pb, He);
  k_scanB<<<(NB*4*DI*NST+255)/256, 256, 0, stream>>>(Pb, He, H0);
  k_scanC<<<dim3(NCH, NB*4, 3), 64, 0, stream>>>(pool, xs, dtw, dtb, alog, Dsv, H0, oy);
  k_out<<<NB*LL, 192, 0, stream>>>(oy, xz, lng, lnb, opw, out);
}

// Round 4
// 320.967 us; speedup vs baseline: 2.1778x; 1.2098x over previous
//
#include <hip/hip_runtime.h>
#include <math.h>

#define LL 3136
#define HH 56
#define WW 56
#define DI 192
#define NB 2
#define NCOUT 38
#define NKO 152
#define NST 16
#define NDTR 6
#define NCH 64     // number of scan chunks
#define CLEN 49    // LL / NCH
#define THETA_C 0.6f

// padded A field: 58x58 pixels, K=384 (t*192+c) contiguous
#define HP 58
#define PIXP (HP*HP)          // 3364
#define KK 384
#define NPAD 160              // padded N for GEMM cols
#define AELEMS ((size_t)NB*PIXP*KK)       // 2,583,552 bf16 per array
#define BPELEMS (9*12*NPAD*32)            // 552,960 per (hi|lo)
#define BDELEMS (12*NPAD*32)              // 61,440 per (hi|lo)
#define PSZ ((size_t)NB*LL*NPAD)          // 1,003,520 floats per partial

typedef short s8v __attribute__((ext_vector_type(8)));
typedef float f4v __attribute__((ext_vector_type(4)));

__device__ __forceinline__ float siluf(float x){ return x * (1.0f / (1.0f + __expf(-x))); }
__device__ __forceinline__ float softplusf(float x){ return (x > 20.0f) ? x : log1pf(__expf(x)); }
__device__ __forceinline__ void split_bf16(float v, unsigned short& hi, unsigned short& lo){
  unsigned bits = __float_as_uint(v);
  hi = (unsigned short)(bits >> 16);
  float hif = __uint_as_float(((unsigned)hi) << 16);
  float lof = v - hif;
  lo = (unsigned short)(__float_as_uint(lof) >> 16);
}

// ---------------- K1: in_proj GEMM  xz[b][e][l] = sum_c x[b,l,c] * w[e,c] ----------------
__global__ __launch_bounds__(512) void k_inproj(const float* __restrict__ x,
                                                const float* __restrict__ w,
                                                float* __restrict__ xz){
  __shared__ float xsh[16][100];
  int bl0 = blockIdx.x * 16;
  int tid = threadIdx.x;
  for (int i = tid; i < 16*96; i += 512){
    xsh[i/96][i%96] = x[(size_t)(bl0 + i/96)*96 + (i%96)];
  }
  __syncthreads();
  int lt = tid & 15, e0 = tid >> 4;   // e0 0..31
  int bl = bl0 + lt;
  int b = bl / LL, l = bl % LL;
  for (int j = 0; j < 12; ++j){
    int e = e0 + 32*j;
    const float* wr = w + e*96;
    float acc = 0.f;
    #pragma unroll
    for (int c = 0; c < 96; c += 4){
      acc += xsh[lt][c]*wr[c] + xsh[lt][c+1]*wr[c+1]
           + xsh[lt][c+2]*wr[c+2] + xsh[lt][c+3]*wr[c+3];
    }
    xz[((size_t)b*384 + e)*LL + l] = acc;
  }
}

// ---------------- K1b: transpose xt (NHWC -> [b][c][l]) ----------------
__global__ __launch_bounds__(256) void k_txt(const float* __restrict__ xt,
                                             float* __restrict__ xtT){
  __shared__ float tile[16][97];
  int l0 = blockIdx.x * 16; int b = blockIdx.y;
  for (int i = threadIdx.x; i < 16*96; i += 256){
    int ll = i / 96, c = i % 96;
    tile[ll][c] = xt[((size_t)b*LL + l0 + ll)*96 + c];
  }
  __syncthreads();
  for (int o = threadIdx.x; o < 96*16; o += 256){
    int c = o >> 4, ll = o & 15;
    xtT[((size_t)b*96 + c)*LL + l0 + ll] = tile[ll][c];
  }
}

// ---------------- K1c: transpose out_proj weight [96][192] -> [192][96] ----------------
__global__ __launch_bounds__(256) void k_topw(const float* __restrict__ opw,
                                              float* __restrict__ opwT){
  int i = blockIdx.x*256 + threadIdx.x;
  if (i >= 96*DI) return;
  int d = i / DI, dd = i % DI;
  opwT[dd*96 + d] = opw[i];
}

// ---------------- K2: depthwise conv 3x3 + bias + SiLU ----------------
__global__ __launch_bounds__(256) void k_conv_xc(const float* __restrict__ xz,
                                                 const float* __restrict__ cw,
                                                 const float* __restrict__ cb,
                                                 float* __restrict__ xc){
  int idx = blockIdx.x*256 + threadIdx.x;
  if (idx >= NB*DI*LL) return;
  int l = idx % LL; int d = (idx / LL) % DI; int b = idx / (DI*LL);
  int h = l / WW, wp = l % WW;
  const float* src = xz + ((size_t)b*384 + d)*LL;
  const float* wk = cw + d*9;
  float acc = cb[d];
  #pragma unroll
  for (int dh = 0; dh < 3; ++dh){
    int hh = h + dh - 1; if (hh < 0 || hh >= HH) continue;
    const float* row = src + hh*WW;
    #pragma unroll
    for (int dw = 0; dw < 3; ++dw){
      int wq = wp + dw - 1; if (wq < 0 || wq >= WW) continue;
      acc += wk[dh*3+dw] * row[wq];
    }
  }
  xc[((size_t)b*DI + d)*LL + l] = siluf(acc);
}

// ---------------- K3: grouped conv on xtT (rows coalesced) ----------------
__global__ __launch_bounds__(256) void k_conv_xt(const float* __restrict__ xtT,
                                                 const float* __restrict__ cw,
                                                 const float* __restrict__ cb,
                                                 float* __restrict__ xtc){
  int idx = blockIdx.x*256 + threadIdx.x;
  if (idx >= NB*DI*LL) return;
  int l = idx % LL; int d = (idx / LL) % DI; int b = idx / (DI*LL);
  int h = l / WW, wp = l % WW;
  int c = d >> 1;
  const float* src = xtT + ((size_t)b*96 + c)*LL;
  const float* wk = cw + d*9;
  float acc = cb[d];
  #pragma unroll
  for (int dh = 0; dh < 3; ++dh){
    int hh = h + dh - 1; if (hh < 0 || hh >= HH) continue;
    const float* row = src + hh*WW;
    #pragma unroll
    for (int dw = 0; dw < 3; ++dw){
      int wq = wp + dw - 1; if (wq < 0 || wq >= WW) continue;
      acc += wk[dh*3+dw] * row[wq];
    }
  }
  xtc[((size_t)b*DI + d)*LL + l] = siluf(acc);
}

// ---------------- K4: pools -> 2 directional base sequences xs[b][dir][l][d] ----------------
__global__ __launch_bounds__(256) void k_xs(const float* __restrict__ xc,
                                            const float* __restrict__ xtc,
                                            float* __restrict__ xs){
  __shared__ float T[4][32][57];
  int h = blockIdx.x, b = blockIdx.y, dt = blockIdx.z;  // dt 0..5
  int d0 = dt*32;
  int i0 = (h >> 1) * 2;
  const float* rsrc = (h & 1) ? xtc : xc;
  for (int i = threadIdx.x; i < 4*32*56; i += 256){
    int pl = i / (32*56); int r = i % (32*56); int dl = r / 56; int w = r % 56;
    const float* s; int row;
    if (pl == 0){ s = xc;  row = h; }
    else if (pl == 1){ s = xtc; row = h; }
    else if (pl == 2){ s = rsrc; row = i0; }
    else { s = rsrc; row = i0 + 1; }
    T[pl][dl][w] = s[((size_t)b*DI + d0 + dl)*LL + row*WW + w];
  }
  __syncthreads();
  for (int o = threadIdx.x; o < 2*56*32; o += 256){
    int out = o / (56*32); int r = o % (56*32); int wp = r / 32; int dl = r & 31;
    if (out == 1){
      int s = wp & 1; int w0 = (wp >> 1) * 2;
      float a0 = T[s][dl][w0], a1 = T[s][dl][w0+1];
      float ic = 0.5f*(a0+a1) + fmaxf(a0,a1);
      xs[(((size_t)b*2 + 1)*LL + h*WW + wp)*DI + d0 + dl] = ic;
    } else {
      float r0 = T[2][dl][wp], r1 = T[3][dl][wp];
      float ir = 0.5f*(r0+r1) + fmaxf(r0,r1);
      xs[(((size_t)b*2 + 0)*LL + wp*HH + h)*DI + d0 + dl] = ir;
    }
  }
}

// ---------------- K5a: kernel_diff[ko][c] ----------------
__global__ __launch_bounds__(256) void k_kd(const float* __restrict__ xpw, float* __restrict__ kd){
  int idx = blockIdx.x*256 + threadIdx.x;
  if (idx >= NKO*DI) return;
  const float* p = xpw + (size_t)idx*18;
  float s = 0.f;
  #pragma unroll
  for (int i = 0; i < 18; ++i) s += p[i];
  kd[idx] = s;
}

// ---------------- K5b: pack weights (fragment layout, hi/lo bf16) ----------------
__global__ __launch_bounds__(256) void k_wpack(const float* __restrict__ xpw,
                                               const float* __restrict__ kd,
                                               unsigned short* __restrict__ Bp,
                                               unsigned short* __restrict__ Bd){
  int idx = blockIdx.x*256 + threadIdx.x;
  if (idx < BPELEMS){
    int q = idx & 31; int n = (idx >> 5) % NPAD; int oks = idx / (NPAD*32);
    int ks = oks % 12, off = oks / 12;
    int k = ks*32 + q;
    int t = k / DI, c = k % DI;
    float v = 0.f;
    if (n < NKO){
      float w = xpw[((size_t)(n*DI + c)*2 + t)*9 + off];
      v = 2.f*w;
      if (off == 4) v -= THETA_C * kd[n*DI + c];
    }
    unsigned short hi, lo; split_bf16(v, hi, lo);
    Bp[idx] = hi; Bp[BPELEMS + idx] = lo;
  } else {
    int id2 = idx - BPELEMS;
    if (id2 >= BDELEMS) return;
    int q = id2 & 31; int n = (id2 >> 5) % NPAD; int ks = id2 / (NPAD*32);
    int k = ks*32 + q;
    int t = k / DI, c = k % DI;
    float v = 0.f;
    if (n < NKO){
      float kv = kd[n*DI + c];
      v = (t == 0) ? kv : -kv;
    }
    unsigned short hi, lo; split_bf16(v, hi, lo);
    Bd[id2] = hi; Bd[BDELEMS + id2] = lo;
  }
}

// ---------------- K5c: pack A (padded 58x58, K contiguous), hi/lo bf16 ----------------
__global__ __launch_bounds__(256) void k_apack(const float* __restrict__ xc,
                                               const float* __restrict__ xtc,
                                               unsigned short* __restrict__ Ah,
                                               unsigned short* __restrict__ Al){
  __shared__ float tile[64*57];
  int h = blockIdx.x, b = blockIdx.y, z = blockIdx.z;
  int t = z / 3, cc = z % 3;
  const float* src = (t ? xtc : xc) + (size_t)b*DI*LL;
  for (int i = threadIdx.x; i < 64*56; i += 256){
    int ci = i / 56, wpx = i % 56;
    tile[ci*57 + wpx] = src[(size_t)(cc*64 + ci)*LL + h*WW + wpx];
  }
  __syncthreads();
  int cl = threadIdx.x & 63, wv = threadIdx.x >> 6;
  for (int wp = wv; wp < WW; wp += 4){
    float v = tile[cl*57 + wp];
    unsigned short hi, lo; split_bf16(v, hi, lo);
    size_t eo = ((size_t)b*PIXP + (size_t)(h+1)*HP + (wp+1))*KK + t*DI + cc*64 + cl;
    Ah[eo] = hi; Al[eo] = lo;
  }
}

// ---------------- K5d: MFMA GEMM v3 — 2 M-frags x 5 N-frags per wave ----------------
// grid (224, 14): bx -> bh = bx>>1 (b*56+h), mh = bx&1 (pixel half 0..31 / 32..63)
//                 g = ch(2) x q(7). q<6: og=q%3 offsets, kh=q/3 K-half -> parts[q]; q==6: diff
__global__ __launch_bounds__(64, 4) void k_gemm(const unsigned short* __restrict__ Ah,
                                                const unsigned short* __restrict__ Al,
                                                const unsigned short* __restrict__ Bp,
                                                const unsigned short* __restrict__ Bd,
                                                float* __restrict__ parts){
  int lane = threadIdx.x;
  int bx = blockIdx.x;
  int g = blockIdx.y;
  int ch = g & 1, q = g >> 1;
  int bh = bx >> 1, mh = bx & 1;
  int b = bh / HH, h = bh % HH;
  int kg = lane >> 4;
  int cl = lane & 15;
  int col = ch*80 + cl;
  int wp0 = mh*32 + cl;          // first m-frag pixel; second is +16

  f4v acc[2][5];
  #pragma unroll
  for (int m = 0; m < 2; ++m)
    #pragma unroll
    for (int nf = 0; nf < 5; ++nf) acc[m][nf] = (f4v){0.f,0.f,0.f,0.f};

  if (q < 6){
    const unsigned short* BpLo = Bp + BPELEMS;
    int og = q % 3, kh = q / 3;
    for (int off = 3*og; off < 3*og + 3; ++off){
      int dh = off / 3, dw = off % 3;
      size_t aB0 = ((size_t)b*PIXP + (size_t)(h+dh)*HP + (wp0+dw))*KK + kg*8;
      size_t aB1 = aB0 + (size_t)16*KK;
      size_t bB0 = ((size_t)(off*12)*NPAD + col)*32 + kg*8;
      for (int ks = 6*kh; ks < 6*kh + 6; ++ks){
        s8v a0h = *(const s8v*)(Ah + aB0 + ks*32);
        s8v a0l = *(const s8v*)(Al + aB0 + ks*32);
        s8v a1h = *(const s8v*)(Ah + aB1 + ks*32);
        s8v a1l = *(const s8v*)(Al + aB1 + ks*32);
        size_t be = bB0 + (size_t)ks*NPAD*32;
        s8v bhv[5], blv[5];
        #pragma unroll
        for (int nf = 0; nf < 5; ++nf){
          bhv[nf] = *(const s8v*)(Bp   + be + (size_t)nf*16*32);
          blv[nf] = *(const s8v*)(BpLo + be + (size_t)nf*16*32);
        }
        #pragma unroll
        for (int nf = 0; nf < 5; ++nf)
          acc[0][nf] = __builtin_amdgcn_mfma_f32_16x16x32_bf16(a0h, bhv[nf], acc[0][nf], 0, 0, 0);
        #pragma unroll
        for (int nf = 0; nf < 5; ++nf)
          acc[1][nf] = __builtin_amdgcn_mfma_f32_16x16x32_bf16(a1h, bhv[nf], acc[1][nf], 0, 0, 0);
        #pragma unroll
        for (int nf = 0; nf < 5; ++nf)
          acc[0][nf] = __builtin_amdgcn_mfma_f32_16x16x32_bf16(a0l, bhv[nf], acc[0][nf], 0, 0, 0);
        #pragma unroll
        for (int nf = 0; nf < 5; ++nf)
          acc[1][nf] = __builtin_amdgcn_mfma_f32_16x16x32_bf16(a1l, bhv[nf], acc[1][nf], 0, 0, 0);
        #pragma unroll
        for (int nf = 0; nf < 5; ++nf)
          acc[0][nf] = __builtin_amdgcn_mfma_f32_16x16x32_bf16(a0h, blv[nf], acc[0][nf], 0, 0, 0);
        #pragma unroll
        for (int nf = 0; nf < 5; ++nf)
          acc[1][nf] = __builtin_amdgcn_mfma_f32_16x16x32_bf16(a1h, blv[nf], acc[1][nf], 0, 0, 0);
      }
    }
  } else {
    const unsigned short* BdLo = Bd + BDELEMS;
    size_t aB0 = ((size_t)b*PIXP + (size_t)(h+1)*HP + (wp0+1))*KK + kg*8;
    size_t aB1 = aB0 + (size_t)16*KK;
    size_t bB0 = ((size_t)col)*32 + kg*8;
    for (int ks = 0; ks < 12; ++ks){
      s8v a0h = *(const s8v*)(Ah + aB0 + ks*32);
      s8v a0l = *(const s8v*)(Al + aB0 + ks*32);
      s8v a1h = *(const s8v*)(Ah + aB1 + ks*32);
      s8v a1l = *(const s8v*)(Al + aB1 + ks*32);
      size_t be = bB0 + (size_t)ks*NPAD*32;
      s8v bhv[5], blv[5];
      #pragma unroll
      for (int nf = 0; nf < 5; ++nf){
        bhv[nf] = *(const s8v*)(Bd   + be + (size_t)nf*16*32);
        blv[nf] = *(const s8v*)(BdLo + be + (size_t)nf*16*32);
      }
      #pragma unroll
      for (int nf = 0; nf < 5; ++nf)
        acc[0][nf] = __builtin_amdgcn_mfma_f32_16x16x32_bf16(a0h, bhv[nf], acc[0][nf], 0, 0, 0);
      #pragma unroll
      for (int nf = 0; nf < 5; ++nf)
        acc[1][nf] = __builtin_amdgcn_mfma_f32_16x16x32_bf16(a1h, bhv[nf], acc[1][nf], 0, 0, 0);
      #pragma unroll
      for (int nf = 0; nf < 5; ++nf)
        acc[0][nf] = __builtin_amdgcn_mfma_f32_16x16x32_bf16(a0l, bhv[nf], acc[0][nf], 0, 0, 0);
      #pragma unroll
      for (int nf = 0; nf < 5; ++nf)
        acc[1][nf] = __builtin_amdgcn_mfma_f32_16x16x32_bf16(a1l, bhv[nf], acc[1][nf], 0, 0, 0);
      #pragma unroll
      for (int nf = 0; nf < 5; ++nf)
        acc[0][nf] = __builtin_amdgcn_mfma_f32_16x16x32_bf16(a0h, blv[nf], acc[0][nf], 0, 0, 0);
      #pragma unroll
      for (int nf = 0; nf < 5; ++nf)
        acc[1][nf] = __builtin_amdgcn_mfma_f32_16x16x32_bf16(a1h, blv[nf], acc[1][nf], 0, 0, 0);
    }
  }

  float* part = parts + (size_t)q*PSZ;
  int r0 = kg * 4;
  #pragma unroll
  for (int m = 0; m < 2; ++m){
    #pragma unroll
    for (int nf = 0; nf < 5; ++nf){
      int c2 = col + nf*16;
      #pragma unroll
      for (int i = 0; i < 4; ++i){
        int wpo = mh*32 + m*16 + r0 + i;
        if (wpo < WW)
          part[((size_t)b*LL + h*WW + wpo)*NPAD + c2] = acc[m][nf][i];
      }
    }
  }
}

// ---------------- K5e: combine partials -> pooled ----------------
__global__ __launch_bounds__(256) void k_pool(const float* __restrict__ parts,
                                              float* __restrict__ pooled){
  int idx = blockIdx.x*256 + threadIdx.x;
  if (idx >= NB*LL*NKO) return;
  int ko = idx % NKO; int l = idx / NKO;
  size_t e = (size_t)l*NPAD + ko;
  float lin = 0.f;
  #pragma unroll
  for (int q = 0; q < 6; ++q) lin += parts[q*PSZ + e];
  float dv = parts[6*PSZ + e];
  float pv = lin + 0.5f*THETA_C*fabsf(dv);
  int b = l / LL, ll = l % LL;
  int k = ko / NCOUT, o = ko % NCOUT;
  pooled[(((size_t)b*4 + k)*LL + ll)*NCOUT + o] = pv;
}

// ---------------- K6a: scan pass A ----------------
__global__ __launch_bounds__(64) void k_scanA(const float* __restrict__ pooled,
                                              const float* __restrict__ xs,
                                              const float* __restrict__ dtw,
                                              const float* __restrict__ dtb,
                                              const float* __restrict__ alog,
                                              float* __restrict__ Pb,
                                              float* __restrict__ He){
  int d = blockIdx.z*64 + threadIdx.x;
  int bk = blockIdx.y;
  int c = blockIdx.x;
  int k = bk & 3, b = bk >> 2;
  int kdix = k*DI + d;
  int dir = (k >> 1) & 1;
  int flip = k & 1;
  float A[NST], P[NST], hst[NST];
  #pragma unroll
  for (int n = 0; n < NST; ++n){ A[n] = -__expf(alog[kdix*NST + n]); P[n] = 1.f; hst[n] = 0.f; }
  float dwv[NDTR];
  #pragma unroll
  for (int r = 0; r < NDTR; ++r) dwv[r] = dtw[kdix*NDTR + r];
  float db = dtb[kdix];
  const float* prow = pooled + ((size_t)bk*LL + c*CLEN)*NCOUT;
  const float* xsd = xs + ((size_t)(b*2 + dir)*LL)*DI + d;
  int pos = c*CLEN;
  int wp = pos % 56, rowb = pos - wp;
  for (int p = 0; p < CLEN; ++p){
    float xr = db;
    #pragma unroll
    for (int r = 0; r < NDTR; ++r) xr += prow[r]*dwv[r];
    float delta = softplusf(xr);
    int upos = flip ? (rowb + 55 - wp) : pos;
    float u = xsd[(size_t)upos*DI];
    float du = delta * u;
    #pragma unroll
    for (int n = 0; n < NST; ++n){
      float dA = __expf(delta * A[n]);
      P[n]  *= dA;
      hst[n] = dA*hst[n] + du*prow[6+n];
    }
    prow += NCOUT;
    ++pos; ++wp; if (wp == 56){ wp = 0; rowb = pos; }
  }
  float* pp = Pb + (((size_t)bk*NCH + c)*DI + d)*NST;
  float* hp = He + (((size_t)bk*NCH + c)*DI + d)*NST;
  #pragma unroll
  for (int n = 0; n < NST; ++n){ pp[n] = P[n]; hp[n] = hst[n]; }
}

// ---------------- K6b: cross-chunk prefix ----------------
__global__ __launch_bounds__(256) void k_scanB(const float* __restrict__ Pb,
                                               const float* __restrict__ He,
                                               float* __restrict__ H0){
  int t = blockIdx.x*256 + threadIdx.x;
  if (t >= NB*4*DI*NST) return;
  int bk = t / (DI*NST);
  int dn = t % (DI*NST);
  float hcur = 0.f;
  for (int c = 0; c < NCH; ++c){
    size_t off = ((size_t)bk*NCH + c)*DI*NST + dn;
    H0[off] = hcur;
    hcur = Pb[off]*hcur + He[off];
  }
}

// ---------------- K6c: scan pass C ----------------
__global__ __launch_bounds__(64) void k_scanC(const float* __restrict__ pooled,
                                              const float* __restrict__ xs,
                                              const float* __restrict__ dtw,
                                              const float* __restrict__ dtb,
                                              const float* __restrict__ alog,
                                              const float* __restrict__ Dsv,
                                              const float* __restrict__ H0,
                                              float* __restrict__ oy){
  int d = blockIdx.z*64 + threadIdx.x;
  int bk = blockIdx.y;
  int c = blockIdx.x;
  int k = bk & 3, b = bk >> 2;
  int kdix = k*DI + d;
  int dir = (k >> 1) & 1;
  int flip = k & 1;
  float A[NST], hst[NST];
  const float* h0p = H0 + (((size_t)bk*NCH + c)*DI + d)*NST;
  #pragma unroll
  for (int n = 0; n < NST; ++n){ A[n] = -__expf(alog[kdix*NST + n]); hst[n] = h0p[n]; }
  float dwv[NDTR];
  #pragma unroll
  for (int r = 0; r < NDTR; ++r) dwv[r] = dtw[kdix*NDTR + r];
  float db = dtb[kdix];
  float Dv = Dsv[kdix];
  const float* prow = pooled + ((size_t)bk*LL + c*CLEN)*NCOUT;
  const float* xsd = xs + ((size_t)(b*2 + dir)*LL)*DI + d;
  float* orow = oy + ((size_t)bk*LL + c*CLEN)*DI + d;
  int pos = c*CLEN;
  int wp = pos % 56, rowb = pos - wp;
  for (int p = 0; p < CLEN; ++p){
    float xr = db;
    #pragma unroll
    for (int r = 0; r < NDTR; ++r) xr += prow[r]*dwv[r];
    float delta = softplusf(xr);
    int upos = flip ? (rowb + 55 - wp) : pos;
    float u = xsd[(size_t)upos*DI];
    float du = delta * u;
    float y = 0.f;
    #pragma unroll
    for (int n = 0; n < NST; ++n){
      float dA = __expf(delta * A[n]);
      hst[n] = dA*hst[n] + du*prow[6+n];
      y += hst[n]*prow[22+n];
    }
    orow[0] = y + Dv*u;
    prow += NCOUT; orow += DI;
    ++pos; ++wp; if (wp == 56){ wp = 0; rowb = pos; }
  }
}

// ---------------- K7: merge + LN + gate + out_proj ----------------
__global__ __launch_bounds__(192) void k_out(const float* __restrict__ oy,
                                             const float* __restrict__ xz,
                                             const float* __restrict__ lng,
                                             const float* __restrict__ lnb,
                                             const float* __restrict__ opwT,
                                             float* __restrict__ out){
  __shared__ float ygs[DI];
  __shared__ float redS[3], redQ[3];
  int bl = blockIdx.x; int b = bl / LL; int l = bl % LL;
  int d = threadIdx.x;
  int h = l / WW, wp = l % WW;
  int p2 = wp*HH + h;
  size_t b4 = (size_t)b*4;
  float y = oy[((b4+0)*LL + l)*DI + d]
          + oy[((b4+2)*LL + (LL-1-l))*DI + d]
          + oy[((b4+1)*LL + p2)*DI + d]
          + oy[((b4+3)*LL + (LL-1-p2))*DI + d];
  float s = y, q = y*y;
  #pragma unroll
  for (int m = 1; m < 64; m <<= 1){ s += __shfl_xor(s, m); q += __shfl_xor(q, m); }
  int wv = d >> 6;
  if ((d & 63) == 0){ redS[wv] = s; redQ[wv] = q; }
  __syncthreads();
  float S = redS[0]+redS[1]+redS[2];
  float Q = redQ[0]+redQ[1]+redQ[2];
  float mu = S * (1.f/DI);
  float var = Q * (1.f/DI) - mu*mu;
  float yn = (y - mu) * rsqrtf(var + 1e-5f) * lng[d] + lnb[d];
  float zv = xz[((size_t)b*384 + 192 + d)*LL + l];
  ygs[d] = yn * siluf(zv);
  __syncthreads();
  if (d < 96){
    float acc = 0.f;
    #pragma unroll 4
    for (int dd = 0; dd < DI; ++dd) acc += ygs[dd] * opwT[dd*96 + d];
    out[(size_t)bl*96 + d] = acc;
  }
}

extern "C" void kernel_launch(void* const* d_in, const int* in_sizes, int n_in,
                              void* d_out, int out_size, void* d_ws, size_t ws_size,
                              hipStream_t stream){
  const float* x    = (const float*)d_in[0];
  const float* xt   = (const float*)d_in[1];
  const float* ipw  = (const float*)d_in[2];
  const float* c2w  = (const float*)d_in[3];
  const float* c2b  = (const float*)d_in[4];
  const float* cxw  = (const float*)d_in[5];
  const float* cxb  = (const float*)d_in[6];
  const float* xpw  = (const float*)d_in[7];
  const float* dtw  = (const float*)d_in[8];
  const float* dtb  = (const float*)d_in[9];
  const float* alog = (const float*)d_in[10];
  const float* Dsv  = (const float*)d_in[11];
  const float* lng  = (const float*)d_in[12];
  const float* lnb  = (const float*)d_in[13];
  const float* opw  = (const float*)d_in[14];
  float* out = (float*)d_out;

  float* ws   = (float*)d_ws;
  float* xz   = ws;                                   // 2,408,448
  float* xc   = xz  + (size_t)NB*384*LL;              // 1,204,224
  float* xtc  = xc  + (size_t)NB*DI*LL;               // 1,204,224
  float* xs   = xtc + (size_t)NB*DI*LL;               // 2,408,448 (2 dirs)
  float* pool = xs  + (size_t)NB*2*LL*DI;             // 953,344
  float* kd   = pool+ (size_t)NB*4*LL*NCOUT;          // 29,184
  float* opwT = kd  + (size_t)NKO*DI;                 // 18,432
  // U1: union of {Ah,Al,Bp,Bd packs} and {Pb,He,H0}
  float* U1   = opwT + (size_t)96*DI;                 // 4,718,592
  float* Pb   = U1;
  float* He   = Pb  + (size_t)NB*4*NCH*DI*NST;
  float* H0   = He  + (size_t)NB*4*NCH*DI*NST;
  unsigned short* Ahi = (unsigned short*)U1;
  unsigned short* Alo = Ahi + AELEMS;
  unsigned short* Bp  = Alo + AELEMS;
  unsigned short* Bd  = Bp + 2*BPELEMS;
  // U2: union of {parts[7]} , {oy} , {xtT in slot 6}
  float* U2   = U1 + 3*(size_t)NB*4*NCH*DI*NST;       // 7,024,640
  float* parts = U2;
  float* oy    = U2;
  float* xtT   = U2 + 6*PSZ;

  hipMemsetAsync((void*)Ahi, 0, 2*AELEMS*sizeof(unsigned short), stream);

  k_inproj<<<NB*LL/16, 512, 0, stream>>>(x, ipw, xz);
  k_txt<<<dim3(LL/16, NB), 256, 0, stream>>>(xt, xtT);
  k_topw<<<(96*DI+255)/256, 256, 0, stream>>>(opw, opwT);
  int n1 = NB*DI*LL;
  k_conv_xc<<<(n1+255)/256, 256, 0, stream>>>(xz, c2w, c2b, xc);
  k_conv_xt<<<(n1+255)/256, 256, 0, stream>>>(xtT, cxw, cxb, xtc);
  k_xs<<<dim3(HH, NB, 6), 256, 0, stream>>>(xc, xtc, xs);
  k_kd<<<(NKO*DI+255)/256, 256, 0, stream>>>(xpw, kd);
  k_wpack<<<(BPELEMS+BDELEMS+255)/256, 256, 0, stream>>>(xpw, kd, Bp, Bd);
  k_apack<<<dim3(HH, NB, 6), 256, 0, stream>>>(xc, xtc, Ahi, Alo);
  k_gemm<<<dim3(224, 14), 64, 0, stream>>>(Ahi, Alo, Bp, Bd, parts);
  k_pool<<<(NB*LL*NKO+255)/256, 256, 0, stream>>>(parts, pool);
  k_scanA<<<dim3(NCH, NB*4, 3), 64, 0, stream>>>(pool, xs, dtw, dtb, alog, Pb, He);
  k_scanB<<<(NB*4*DI*NST+255)/256, 256, 0, stream>>>(Pb, He, H0);
  k_scanC<<<dim3(NCH, NB*4, 3), 64, 0, stream>>>(pool, xs, dtw, dtb, alog, Dsv, H0, oy);
  k_out<<<NB*LL, 192, 0, stream>>>(oy, xz, lng, lnb, opwT, out);
}

// Round 5
// 309.602 us; speedup vs baseline: 2.2578x; 1.0367x over previous
//
#include <hip/hip_runtime.h>
#include <math.h>

#define LL 3136
#define HH 56
#define WW 56
#define DI 192
#define NB 2
#define NCOUT 38
#define NKO 152
#define NST 16
#define NDTR 6
#define NCH 64     // number of scan chunks
#define CLEN 49    // LL / NCH
#define THETA_C 0.6f

// padded A field: 58x58 pixels, K=384 (t*192+c) contiguous
#define HP 58
#define PIXP (HP*HP)          // 3364
#define KK 384
#define NPAD 160              // padded N for GEMM cols
#define AELEMS ((size_t)NB*PIXP*KK)       // 2,583,552 bf16 per array
#define BPELEMS (9*12*NPAD*32)            // 552,960 per (hi|lo)
#define BDELEMS (12*NPAD*32)              // 61,440 per (hi|lo)
#define PSZ ((size_t)NB*LL*NPAD)          // 1,003,520 floats per partial

typedef short s8v __attribute__((ext_vector_type(8)));
typedef float f4v __attribute__((ext_vector_type(4)));

__device__ __forceinline__ float siluf(float x){ return x * (1.0f / (1.0f + __expf(-x))); }
__device__ __forceinline__ float softplusf(float x){ return (x > 20.0f) ? x : log1pf(__expf(x)); }
__device__ __forceinline__ void split_bf16(float v, unsigned short& hi, unsigned short& lo){
  unsigned bits = __float_as_uint(v);
  hi = (unsigned short)(bits >> 16);
  float hif = __uint_as_float(((unsigned)hi) << 16);
  float lof = v - hif;
  lo = (unsigned short)(__float_as_uint(lof) >> 16);
}

// ---------------- K1: in_proj GEMM ----------------
__global__ __launch_bounds__(512) void k_inproj(const float* __restrict__ x,
                                                const float* __restrict__ w,
                                                float* __restrict__ xz){
  __shared__ float xsh[16][100];
  int bl0 = blockIdx.x * 16;
  int tid = threadIdx.x;
  for (int i = tid; i < 16*96; i += 512){
    xsh[i/96][i%96] = x[(size_t)(bl0 + i/96)*96 + (i%96)];
  }
  __syncthreads();
  int lt = tid & 15, e0 = tid >> 4;
  int bl = bl0 + lt;
  int b = bl / LL, l = bl % LL;
  for (int j = 0; j < 12; ++j){
    int e = e0 + 32*j;
    const float* wr = w + e*96;
    float acc = 0.f;
    #pragma unroll
    for (int c = 0; c < 96; c += 4){
      acc += xsh[lt][c]*wr[c] + xsh[lt][c+1]*wr[c+1]
           + xsh[lt][c+2]*wr[c+2] + xsh[lt][c+3]*wr[c+3];
    }
    xz[((size_t)b*384 + e)*LL + l] = acc;
  }
}

// ---------------- K1b: transpose xt (NHWC -> [b][c][l]) ----------------
__global__ __launch_bounds__(256) void k_txt(const float* __restrict__ xt,
                                             float* __restrict__ xtT){
  __shared__ float tile[16][97];
  int l0 = blockIdx.x * 16; int b = blockIdx.y;
  for (int i = threadIdx.x; i < 16*96; i += 256){
    int ll = i / 96, c = i % 96;
    tile[ll][c] = xt[((size_t)b*LL + l0 + ll)*96 + c];
  }
  __syncthreads();
  for (int o = threadIdx.x; o < 96*16; o += 256){
    int c = o >> 4, ll = o & 15;
    xtT[((size_t)b*96 + c)*LL + l0 + ll] = tile[ll][c];
  }
}

// ---------------- K1c: transpose out_proj weight ----------------
__global__ __launch_bounds__(256) void k_topw(const float* __restrict__ opw,
                                              float* __restrict__ opwT){
  int i = blockIdx.x*256 + threadIdx.x;
  if (i >= 96*DI) return;
  int d = i / DI, dd = i % DI;
  opwT[dd*96 + d] = opw[i];
}

// ---------------- K1d: zero only the border pixels of the padded A field ----------------
__global__ __launch_bounds__(256) void k_azero(unsigned short* __restrict__ Ah,
                                               unsigned short* __restrict__ Al){
  const int TOT = NB*228*96;           // 8B-stores per array
  int i = blockIdx.x*256 + threadIdx.x;
  if (i >= 2*TOT) return;
  int arr = i / TOT; int r = i % TOT;
  int k8 = r % 96; r /= 96;
  int b = r / 228; int pi = r % 228;
  int row, col;
  if (pi < 58){ row = 0; col = pi; }
  else if (pi < 116){ row = 57; col = pi - 58; }
  else if (pi < 172){ row = pi - 115; col = 0; }
  else { row = pi - 171; col = 57; }
  unsigned short* p = (arr ? Al : Ah) + ((size_t)b*PIXP + (size_t)row*HP + col)*KK + k8*4;
  *(unsigned long long*)p = 0ULL;
}

// ---------------- K2: fused depthwise conv (xc) + grouped conv (xtc) ----------------
__global__ __launch_bounds__(256) void k_conv(const float* __restrict__ xz,
                                              const float* __restrict__ xtT,
                                              const float* __restrict__ c2w,
                                              const float* __restrict__ c2b,
                                              const float* __restrict__ cxw,
                                              const float* __restrict__ cxb,
                                              float* __restrict__ xc,
                                              float* __restrict__ xtc){
  const int n1 = NB*DI*LL;
  int idx = blockIdx.x*256 + threadIdx.x;
  if (idx >= 2*n1) return;
  int isXT = idx >= n1;
  int id = isXT ? idx - n1 : idx;
  int l = id % LL; int d = (id / LL) % DI; int b = id / (DI*LL);
  int h = l / WW, wp = l % WW;
  const float* src; const float* wk; float acc;
  if (!isXT){
    src = xz + ((size_t)b*384 + d)*LL;
    wk = c2w + d*9; acc = c2b[d];
  } else {
    src = xtT + ((size_t)b*96 + (d >> 1))*LL;
    wk = cxw + d*9; acc = cxb[d];
  }
  #pragma unroll
  for (int dh = 0; dh < 3; ++dh){
    int hh = h + dh - 1; if (hh < 0 || hh >= HH) continue;
    const float* row = src + hh*WW;
    #pragma unroll
    for (int dw = 0; dw < 3; ++dw){
      int wq = wp + dw - 1; if (wq < 0 || wq >= WW) continue;
      acc += wk[dh*3+dw] * row[wq];
    }
  }
  (isXT ? xtc : xc)[((size_t)b*DI + d)*LL + l] = siluf(acc);
}

// ---------------- K4: pools -> 2 directional base sequences ----------------
__global__ __launch_bounds__(256) void k_xs(const float* __restrict__ xc,
                                            const float* __restrict__ xtc,
                                            float* __restrict__ xs){
  __shared__ float T[4][32][57];
  int h = blockIdx.x, b = blockIdx.y, dt = blockIdx.z;
  int d0 = dt*32;
  int i0 = (h >> 1) * 2;
  const float* rsrc = (h & 1) ? xtc : xc;
  for (int i = threadIdx.x; i < 4*32*56; i += 256){
    int pl = i / (32*56); int r = i % (32*56); int dl = r / 56; int w = r % 56;
    const float* s; int row;
    if (pl == 0){ s = xc;  row = h; }
    else if (pl == 1){ s = xtc; row = h; }
    else if (pl == 2){ s = rsrc; row = i0; }
    else { s = rsrc; row = i0 + 1; }
    T[pl][dl][w] = s[((size_t)b*DI + d0 + dl)*LL + row*WW + w];
  }
  __syncthreads();
  for (int o = threadIdx.x; o < 2*56*32; o += 256){
    int out = o / (56*32); int r = o % (56*32); int wp = r / 32; int dl = r & 31;
    if (out == 1){
      int s = wp & 1; int w0 = (wp >> 1) * 2;
      float a0 = T[s][dl][w0], a1 = T[s][dl][w0+1];
      float ic = 0.5f*(a0+a1) + fmaxf(a0,a1);
      xs[(((size_t)b*2 + 1)*LL + h*WW + wp)*DI + d0 + dl] = ic;
    } else {
      float r0 = T[2][dl][wp], r1 = T[3][dl][wp];
      float ir = 0.5f*(r0+r1) + fmaxf(r0,r1);
      xs[(((size_t)b*2 + 0)*LL + wp*HH + h)*DI + d0 + dl] = ir;
    }
  }
}

// ---------------- K5a: kernel_diff ----------------
__global__ __launch_bounds__(256) void k_kd(const float* __restrict__ xpw, float* __restrict__ kd){
  int idx = blockIdx.x*256 + threadIdx.x;
  if (idx >= NKO*DI) return;
  const float* p = xpw + (size_t)idx*18;
  float s = 0.f;
  #pragma unroll
  for (int i = 0; i < 18; ++i) s += p[i];
  kd[idx] = s;
}

// ---------------- K5b: pack weights ----------------
__global__ __launch_bounds__(256) void k_wpack(const float* __restrict__ xpw,
                                               const float* __restrict__ kd,
                                               unsigned short* __restrict__ Bp,
                                               unsigned short* __restrict__ Bd){
  int idx = blockIdx.x*256 + threadIdx.x;
  if (idx < BPELEMS){
    int q = idx & 31; int n = (idx >> 5) % NPAD; int oks = idx / (NPAD*32);
    int ks = oks % 12, off = oks / 12;
    int k = ks*32 + q;
    int t = k / DI, c = k % DI;
    float v = 0.f;
    if (n < NKO){
      float w = xpw[((size_t)(n*DI + c)*2 + t)*9 + off];
      v = 2.f*w;
      if (off == 4) v -= THETA_C * kd[n*DI + c];
    }
    unsigned short hi, lo; split_bf16(v, hi, lo);
    Bp[idx] = hi; Bp[BPELEMS + idx] = lo;
  } else {
    int id2 = idx - BPELEMS;
    if (id2 >= BDELEMS) return;
    int q = id2 & 31; int n = (id2 >> 5) % NPAD; int ks = id2 / (NPAD*32);
    int k = ks*32 + q;
    int t = k / DI, c = k % DI;
    float v = 0.f;
    if (n < NKO){
      float kv = kd[n*DI + c];
      v = (t == 0) ? kv : -kv;
    }
    unsigned short hi, lo; split_bf16(v, hi, lo);
    Bd[id2] = hi; Bd[BDELEMS + id2] = lo;
  }
}

// ---------------- K5c: pack A ----------------
__global__ __launch_bounds__(256) void k_apack(const float* __restrict__ xc,
                                               const float* __restrict__ xtc,
                                               unsigned short* __restrict__ Ah,
                                               unsigned short* __restrict__ Al){
  __shared__ float tile[64*57];
  int h = blockIdx.x, b = blockIdx.y, z = blockIdx.z;
  int t = z / 3, cc = z % 3;
  const float* src = (t ? xtc : xc) + (size_t)b*DI*LL;
  for (int i = threadIdx.x; i < 64*56; i += 256){
    int ci = i / 56, wpx = i % 56;
    tile[ci*57 + wpx] = src[(size_t)(cc*64 + ci)*LL + h*WW + wpx];
  }
  __syncthreads();
  int cl = threadIdx.x & 63, wv = threadIdx.x >> 6;
  for (int wp = wv; wp < WW; wp += 4){
    float v = tile[cl*57 + wp];
    unsigned short hi, lo; split_bf16(v, hi, lo);
    size_t eo = ((size_t)b*PIXP + (size_t)(h+1)*HP + (wp+1))*KK + t*DI + cc*64 + cl;
    Ah[eo] = hi; Al[eo] = lo;
  }
}

// ---------------- K5d: MFMA GEMM v4 — register double-buffered pipeline ----------------
struct Frags {
  s8v a0h, a0l, a1h, a1l;
  s8v bh[5];
  s8v bl[5];
};

__device__ __forceinline__ void load_frags(Frags& f,
    const unsigned short* __restrict__ Ah, const unsigned short* __restrict__ Al,
    const unsigned short* __restrict__ Bh, const unsigned short* __restrict__ Bl,
    size_t aOff, size_t bOff){
  f.a0h = *(const s8v*)(Ah + aOff);
  f.a0l = *(const s8v*)(Al + aOff);
  f.a1h = *(const s8v*)(Ah + aOff + (size_t)16*KK);
  f.a1l = *(const s8v*)(Al + aOff + (size_t)16*KK);
  #pragma unroll
  for (int nf = 0; nf < 5; ++nf){
    f.bh[nf] = *(const s8v*)(Bh + bOff + (size_t)nf*16*32);
    f.bl[nf] = *(const s8v*)(Bl + bOff + (size_t)nf*16*32);
  }
}

__device__ __forceinline__ void mfma_all(const Frags& f, f4v (&acc)[2][5]){
  #pragma unroll
  for (int nf = 0; nf < 5; ++nf)
    acc[0][nf] = __builtin_amdgcn_mfma_f32_16x16x32_bf16(f.a0h, f.bh[nf], acc[0][nf], 0, 0, 0);
  #pragma unroll
  for (int nf = 0; nf < 5; ++nf)
    acc[1][nf] = __builtin_amdgcn_mfma_f32_16x16x32_bf16(f.a1h, f.bh[nf], acc[1][nf], 0, 0, 0);
  #pragma unroll
  for (int nf = 0; nf < 5; ++nf)
    acc[0][nf] = __builtin_amdgcn_mfma_f32_16x16x32_bf16(f.a0l, f.bh[nf], acc[0][nf], 0, 0, 0);
  #pragma unroll
  for (int nf = 0; nf < 5; ++nf)
    acc[1][nf] = __builtin_amdgcn_mfma_f32_16x16x32_bf16(f.a1l, f.bh[nf], acc[1][nf], 0, 0, 0);
  #pragma unroll
  for (int nf = 0; nf < 5; ++nf)
    acc[0][nf] = __builtin_amdgcn_mfma_f32_16x16x32_bf16(f.a0h, f.bl[nf], acc[0][nf], 0, 0, 0);
  #pragma unroll
  for (int nf = 0; nf < 5; ++nf)
    acc[1][nf] = __builtin_amdgcn_mfma_f32_16x16x32_bf16(f.a1h, f.bl[nf], acc[1][nf], 0, 0, 0);
}

__global__ __launch_bounds__(64, 2) void k_gemm(const unsigned short* __restrict__ Ah,
                                                const unsigned short* __restrict__ Al,
                                                const unsigned short* __restrict__ Bp,
                                                const unsigned short* __restrict__ Bd,
                                                float* __restrict__ parts){
  int lane = threadIdx.x;
  int bx = blockIdx.x;
  int g = blockIdx.y;
  int ch = g & 1, q = g >> 1;
  int bh = bx >> 1, mh = bx & 1;
  int b = bh / HH, h = bh % HH;
  int kg = lane >> 4;
  int cl = lane & 15;
  int col = ch*80 + cl;
  int wp0 = mh*32 + cl;

  f4v acc[2][5];
  #pragma unroll
  for (int m = 0; m < 2; ++m)
    #pragma unroll
    for (int nf = 0; nf < 5; ++nf) acc[m][nf] = (f4v){0.f,0.f,0.f,0.f};

  Frags f0, f1;
  if (q < 6){
    const unsigned short* BpLo = Bp + BPELEMS;
    int og = q % 3, kh = q / 3;
    size_t aRow = ((size_t)b*PIXP + (size_t)(h+og)*HP + wp0)*KK + kg*8;
    size_t bCol = (size_t)col*32 + kg*8;
    // step s: dw = s/6, ks = 6*kh + s%6
    #define AOFF(s) (aRow + (size_t)((s)/6)*KK + (size_t)(6*kh + (s)%6)*32)
    #define BOFF(s) (bCol + (size_t)(((3*og + (s)/6)*12) + 6*kh + (s)%6)*NPAD*32)
    load_frags(f0, Ah, Al, Bp, BpLo, AOFF(0), BOFF(0));
    for (int s = 0; s < 18; s += 2){
      load_frags(f1, Ah, Al, Bp, BpLo, AOFF(s+1), BOFF(s+1));
      mfma_all(f0, acc);
      if (s + 2 < 18) load_frags(f0, Ah, Al, Bp, BpLo, AOFF(s+2), BOFF(s+2));
      mfma_all(f1, acc);
    }
    #undef AOFF
    #undef BOFF
  } else {
    const unsigned short* BdLo = Bd + BDELEMS;
    size_t aRow = ((size_t)b*PIXP + (size_t)(h+1)*HP + (wp0+1))*KK + kg*8;
    size_t bCol = (size_t)col*32 + kg*8;
    #define AOFF(s) (aRow + (size_t)(s)*32)
    #define BOFF(s) (bCol + (size_t)(s)*NPAD*32)
    load_frags(f0, Ah, Al, Bd, BdLo, AOFF(0), BOFF(0));
    for (int s = 0; s < 12; s += 2){
      load_frags(f1, Ah, Al, Bd, BdLo, AOFF(s+1), BOFF(s+1));
      mfma_all(f0, acc);
      if (s + 2 < 12) load_frags(f0, Ah, Al, Bd, BdLo, AOFF(s+2), BOFF(s+2));
      mfma_all(f1, acc);
    }
    #undef AOFF
    #undef BOFF
  }

  float* part = parts + (size_t)q*PSZ;
  int r0 = kg * 4;
  #pragma unroll
  for (int m = 0; m < 2; ++m){
    #pragma unroll
    for (int nf = 0; nf < 5; ++nf){
      int c2 = col + nf*16;
      #pragma unroll
      for (int i = 0; i < 4; ++i){
        int wpo = mh*32 + m*16 + r0 + i;
        if (wpo < WW)
          part[((size_t)b*LL + h*WW + wpo)*NPAD + c2] = acc[m][nf][i];
      }
    }
  }
}

// ---------------- K5e: combine partials -> pooled ----------------
__global__ __launch_bounds__(256) void k_pool(const float* __restrict__ parts,
                                              float* __restrict__ pooled){
  int idx = blockIdx.x*256 + threadIdx.x;
  if (idx >= NB*LL*NKO) return;
  int ko = idx % NKO; int l = idx / NKO;
  size_t e = (size_t)l*NPAD + ko;
  float lin = 0.f;
  #pragma unroll
  for (int q = 0; q < 6; ++q) lin += parts[q*PSZ + e];
  float dv = parts[6*PSZ + e];
  float pv = lin + 0.5f*THETA_C*fabsf(dv);
  int b = l / LL, ll = l % LL;
  int k = ko / NCOUT, o = ko % NCOUT;
  pooled[(((size_t)b*4 + k)*LL + ll)*NCOUT + o] = pv;
}

// ---------------- K6a: scan pass A ----------------
__global__ __launch_bounds__(64) void k_scanA(const float* __restrict__ pooled,
                                              const float* __restrict__ xs,
                                              const float* __restrict__ dtw,
                                              const float* __restrict__ dtb,
                                              const float* __restrict__ alog,
                                              float* __restrict__ Pb,
                                              float* __restrict__ He){
  int d = blockIdx.z*64 + threadIdx.x;
  int bk = blockIdx.y;
  int c = blockIdx.x;
  int k = bk & 3, b = bk >> 2;
  int kdix = k*DI + d;
  int dir = (k >> 1) & 1;
  int flip = k & 1;
  float A[NST], P[NST], hst[NST];
  #pragma unroll
  for (int n = 0; n < NST; ++n){ A[n] = -__expf(alog[kdix*NST + n]); P[n] = 1.f; hst[n] = 0.f; }
  float dwv[NDTR];
  #pragma unroll
  for (int r = 0; r < NDTR; ++r) dwv[r] = dtw[kdix*NDTR + r];
  float db = dtb[kdix];
  const float* prow = pooled + ((size_t)bk*LL + c*CLEN)*NCOUT;
  const float* xsd = xs + ((size_t)(b*2 + dir)*LL)*DI + d;
  int pos = c*CLEN;
  int wp = pos % 56, rowb = pos - wp;
  for (int p = 0; p < CLEN; ++p){
    float xr = db;
    #pragma unroll
    for (int r = 0; r < NDTR; ++r) xr += prow[r]*dwv[r];
    float delta = softplusf(xr);
    int upos = flip ? (rowb + 55 - wp) : pos;
    float u = xsd[(size_t)upos*DI];
    float du = delta * u;
    #pragma unroll
    for (int n = 0; n < NST; ++n){
      float dA = __expf(delta * A[n]);
      P[n]  *= dA;
      hst[n] = dA*hst[n] + du*prow[6+n];
    }
    prow += NCOUT;
    ++pos; ++wp; if (wp == 56){ wp = 0; rowb = pos; }
  }
  float* pp = Pb + (((size_t)bk*NCH + c)*DI + d)*NST;
  float* hp = He + (((size_t)bk*NCH + c)*DI + d)*NST;
  #pragma unroll
  for (int n = 0; n < NST; ++n){ pp[n] = P[n]; hp[n] = hst[n]; }
}

// ---------------- K6b: cross-chunk prefix ----------------
__global__ __launch_bounds__(256) void k_scanB(const float* __restrict__ Pb,
                                               const float* __restrict__ He,
                                               float* __restrict__ H0){
  int t = blockIdx.x*256 + threadIdx.x;
  if (t >= NB*4*DI*NST) return;
  int bk = t / (DI*NST);
  int dn = t % (DI*NST);
  float hcur = 0.f;
  for (int c = 0; c < NCH; ++c){
    size_t off = ((size_t)bk*NCH + c)*DI*NST + dn;
    H0[off] = hcur;
    hcur = Pb[off]*hcur + He[off];
  }
}

// ---------------- K6c: scan pass C ----------------
__global__ __launch_bounds__(64) void k_scanC(const float* __restrict__ pooled,
                                              const float* __restrict__ xs,
                                              const float* __restrict__ dtw,
                                              const float* __restrict__ dtb,
                                              const float* __restrict__ alog,
                                              const float* __restrict__ Dsv,
                                              const float* __restrict__ H0,
                                              float* __restrict__ oy){
  int d = blockIdx.z*64 + threadIdx.x;
  int bk = blockIdx.y;
  int c = blockIdx.x;
  int k = bk & 3, b = bk >> 2;
  int kdix = k*DI + d;
  int dir = (k >> 1) & 1;
  int flip = k & 1;
  float A[NST], hst[NST];
  const float* h0p = H0 + (((size_t)bk*NCH + c)*DI + d)*NST;
  #pragma unroll
  for (int n = 0; n < NST; ++n){ A[n] = -__expf(alog[kdix*NST + n]); hst[n] = h0p[n]; }
  float dwv[NDTR];
  #pragma unroll
  for (int r = 0; r < NDTR; ++r) dwv[r] = dtw[kdix*NDTR + r];
  float db = dtb[kdix];
  float Dv = Dsv[kdix];
  const float* prow = pooled + ((size_t)bk*LL + c*CLEN)*NCOUT;
  const float* xsd = xs + ((size_t)(b*2 + dir)*LL)*DI + d;
  float* orow = oy + ((size_t)bk*LL + c*CLEN)*DI + d;
  int pos = c*CLEN;
  int wp = pos % 56, rowb = pos - wp;
  for (int p = 0; p < CLEN; ++p){
    float xr = db;
    #pragma unroll
    for (int r = 0; r < NDTR; ++r) xr += prow[r]*dwv[r];
    float delta = softplusf(xr);
    int upos = flip ? (rowb + 55 - wp) : pos;
    float u = xsd[(size_t)upos*DI];
    float du = delta * u;
    float y = 0.f;
    #pragma unroll
    for (int n = 0; n < NST; ++n){
      float dA = __expf(delta * A[n]);
      hst[n] = dA*hst[n] + du*prow[6+n];
      y += hst[n]*prow[22+n];
    }
    orow[0] = y + Dv*u;
    prow += NCOUT; orow += DI;
    ++pos; ++wp; if (wp == 56){ wp = 0; rowb = pos; }
  }
}

// ---------------- K7: merge + LN + gate + out_proj (split dot) ----------------
__global__ __launch_bounds__(192) void k_out(const float* __restrict__ oy,
                                             const float* __restrict__ xz,
                                             const float* __restrict__ lng,
                                             const float* __restrict__ lnb,
                                             const float* __restrict__ opwT,
                                             float* __restrict__ out){
  __shared__ float ygs[DI];
  __shared__ float pacc[96];
  __shared__ float redS[3], redQ[3];
  int bl = blockIdx.x; int b = bl / LL; int l = bl % LL;
  int d = threadIdx.x;
  int h = l / WW, wp = l % WW;
  int p2 = wp*HH + h;
  size_t b4 = (size_t)b*4;
  float y = oy[((b4+0)*LL + l)*DI + d]
          + oy[((b4+2)*LL + (LL-1-l))*DI + d]
          + oy[((b4+1)*LL + p2)*DI + d]
          + oy[((b4+3)*LL + (LL-1-p2))*DI + d];
  float s = y, q = y*y;
  #pragma unroll
  for (int m = 1; m < 64; m <<= 1){ s += __shfl_xor(s, m); q += __shfl_xor(q, m); }
  int wv = d >> 6;
  if ((d & 63) == 0){ redS[wv] = s; redQ[wv] = q; }
  __syncthreads();
  float S = redS[0]+redS[1]+redS[2];
  float Q = redQ[0]+redQ[1]+redQ[2];
  float mu = S * (1.f/DI);
  float var = Q * (1.f/DI) - mu*mu;
  float yn = (y - mu) * rsqrtf(var + 1e-5f) * lng[d] + lnb[d];
  float zv = xz[((size_t)b*384 + 192 + d)*LL + l];
  ygs[d] = yn * siluf(zv);
  __syncthreads();
  int half = d / 96, dc = d - half*96;
  float acc = 0.f;
  int dd0 = half * 96;
  #pragma unroll 8
  for (int dd = dd0; dd < dd0 + 96; ++dd) acc += ygs[dd] * opwT[dd*96 + dc];
  if (half) pacc[dc] = acc;
  __syncthreads();
  if (!half) out[(size_t)bl*96 + dc] = acc + pacc[dc];
}

extern "C" void kernel_launch(void* const* d_in, const int* in_sizes, int n_in,
                              void* d_out, int out_size, void* d_ws, size_t ws_size,
                              hipStream_t stream){
  const float* x    = (const float*)d_in[0];
  const float* xt   = (const float*)d_in[1];
  const float* ipw  = (const float*)d_in[2];
  const float* c2w  = (const float*)d_in[3];
  const float* c2b  = (const float*)d_in[4];
  const float* cxw  = (const float*)d_in[5];
  const float* cxb  = (const float*)d_in[6];
  const float* xpw  = (const float*)d_in[7];
  const float* dtw  = (const float*)d_in[8];
  const float* dtb  = (const float*)d_in[9];
  const float* alog = (const float*)d_in[10];
  const float* Dsv  = (const float*)d_in[11];
  const float* lng  = (const float*)d_in[12];
  const float* lnb  = (const float*)d_in[13];
  const float* opw  = (const float*)d_in[14];
  float* out = (float*)d_out;

  float* ws   = (float*)d_ws;
  float* xz   = ws;
  float* xc   = xz  + (size_t)NB*384*LL;
  float* xtc  = xc  + (size_t)NB*DI*LL;
  float* xs   = xtc + (size_t)NB*DI*LL;
  float* pool = xs  + (size_t)NB*2*LL*DI;
  float* kd   = pool+ (size_t)NB*4*LL*NCOUT;
  float* opwT = kd  + (size_t)NKO*DI;
  float* U1   = opwT + (size_t)96*DI;
  float* Pb   = U1;
  float* He   = Pb  + (size_t)NB*4*NCH*DI*NST;
  float* H0   = He  + (size_t)NB*4*NCH*DI*NST;
  unsigned short* Ahi = (unsigned short*)U1;
  unsigned short* Alo = Ahi + AELEMS;
  unsigned short* Bp  = Alo + AELEMS;
  unsigned short* Bd  = Bp + 2*BPELEMS;
  float* U2   = U1 + 3*(size_t)NB*4*NCH*DI*NST;
  float* parts = U2;
  float* oy    = U2;
  float* xtT   = U2 + 6*PSZ;   // aliases parts[6] (diff), written by gemm AFTER conv consumed xtT

  k_azero<<<(2*NB*228*96 + 255)/256, 256, 0, stream>>>(Ahi, Alo);
  k_inproj<<<NB*LL/16, 512, 0, stream>>>(x, ipw, xz);
  k_txt<<<dim3(LL/16, NB), 256, 0, stream>>>(xt, xtT);
  k_topw<<<(96*DI+255)/256, 256, 0, stream>>>(opw, opwT);
  int n1 = NB*DI*LL;
  k_conv<<<(2*n1+255)/256, 256, 0, stream>>>(xz, xtT, c2w, c2b, cxw, cxb, xc, xtc);
  k_xs<<<dim3(HH, NB, 6), 256, 0, stream>>>(xc, xtc, xs);
  k_kd<<<(NKO*DI+255)/256, 256, 0, stream>>>(xpw, kd);
  k_wpack<<<(BPELEMS+BDELEMS+255)/256, 256, 0, stream>>>(xpw, kd, Bp, Bd);
  k_apack<<<dim3(HH, NB, 6), 256, 0, stream>>>(xc, xtc, Ahi, Alo);
  k_gemm<<<dim3(224, 14), 64, 0, stream>>>(Ahi, Alo, Bp, Bd, parts);
  k_pool<<<(NB*LL*NKO+255)/256, 256, 0, stream>>>(parts, pool);
  k_scanA<<<dim3(NCH, NB*4, 3), 64, 0, stream>>>(pool, xs, dtw, dtb, alog, Pb, He);
  k_scanB<<<(NB*4*DI*NST+255)/256, 256, 0, stream>>>(Pb, He, H0);
  k_scanC<<<dim3(NCH, NB*4, 3), 64, 0, stream>>>(pool, xs, dtw, dtb, alog, Dsv, H0, oy);
  k_out<<<NB*LL, 192, 0, stream>>>(oy, xz, lng, lnb, opwT, out);
}

// Round 6
// 291.818 us; speedup vs baseline: 2.3953x; 1.0609x over previous
//
#include <hip/hip_runtime.h>
#include <math.h>

#define LL 3136
#define HH 56
#define WW 56
#define DI 192
#define NB 2
#define NCOUT 38
#define NKO 152
#define NST 16
#define NDTR 6
#define NCH 64     // number of scan chunks
#define CLEN 49    // LL / NCH
#define THETA_C 0.6f

// padded A field: 58x58 pixels, K=384 (t*192+c) contiguous
#define HP 58
#define PIXP (HP*HP)          // 3364
#define KK 384
#define NPAD 160              // padded N for GEMM cols
#define AELEMS ((size_t)NB*PIXP*KK)       // 2,583,552 bf16 per array
#define BPELEMS (9*12*NPAD*32)            // 552,960 per (hi|lo)
#define BDELEMS (12*NPAD*32)              // 61,440 per (hi|lo)
#define PSZ ((size_t)NB*LL*NPAD)          // 1,003,520 floats per partial
#define AZTOT (2*NB*228*96)               // 87,552 border-zero slots
#define TOPWN (96*DI)                     // 18,432

typedef short s8v __attribute__((ext_vector_type(8)));
typedef float f4v __attribute__((ext_vector_type(4)));

__device__ __forceinline__ float siluf(float x){ return x * (1.0f / (1.0f + __expf(-x))); }
__device__ __forceinline__ float softplusf(float x){ return (x > 20.0f) ? x : log1pf(__expf(x)); }
__device__ __forceinline__ void split_bf16(float v, unsigned short& hi, unsigned short& lo){
  unsigned bits = __float_as_uint(v);
  hi = (unsigned short)(bits >> 16);
  float hif = __uint_as_float(((unsigned)hi) << 16);
  float lof = v - hif;
  lo = (unsigned short)(__float_as_uint(lof) >> 16);
}

// ---------------- K1: in_proj GEMM ----------------
__global__ __launch_bounds__(512) void k_inproj(const float* __restrict__ x,
                                                const float* __restrict__ w,
                                                float* __restrict__ xz){
  __shared__ float xsh[16][100];
  int bl0 = blockIdx.x * 16;
  int tid = threadIdx.x;
  for (int i = tid; i < 16*96; i += 512){
    xsh[i/96][i%96] = x[(size_t)(bl0 + i/96)*96 + (i%96)];
  }
  __syncthreads();
  int lt = tid & 15, e0 = tid >> 4;
  int bl = bl0 + lt;
  int b = bl / LL, l = bl % LL;
  for (int j = 0; j < 12; ++j){
    int e = e0 + 32*j;
    const float* wr = w + e*96;
    float acc = 0.f;
    #pragma unroll
    for (int c = 0; c < 96; c += 4){
      acc += xsh[lt][c]*wr[c] + xsh[lt][c+1]*wr[c+1]
           + xsh[lt][c+2]*wr[c+2] + xsh[lt][c+3]*wr[c+3];
    }
    xz[((size_t)b*384 + e)*LL + l] = acc;
  }
}

// ---------------- K1b: transpose xt (NHWC -> [b][c][l]) ----------------
__global__ __launch_bounds__(256) void k_txt(const float* __restrict__ xt,
                                             float* __restrict__ xtT){
  __shared__ float tile[16][97];
  int l0 = blockIdx.x * 16; int b = blockIdx.y;
  for (int i = threadIdx.x; i < 16*96; i += 256){
    int ll = i / 96, c = i % 96;
    tile[ll][c] = xt[((size_t)b*LL + l0 + ll)*96 + c];
  }
  __syncthreads();
  for (int o = threadIdx.x; o < 96*16; o += 256){
    int c = o >> 4, ll = o & 15;
    xtT[((size_t)b*96 + c)*LL + l0 + ll] = tile[ll][c];
  }
}

// ---------------- K2: fused depthwise conv (xc) + grouped conv (xtc) ----------------
__global__ __launch_bounds__(256) void k_conv(const float* __restrict__ xz,
                                              const float* __restrict__ xtT,
                                              const float* __restrict__ c2w,
                                              const float* __restrict__ c2b,
                                              const float* __restrict__ cxw,
                                              const float* __restrict__ cxb,
                                              float* __restrict__ xc,
                                              float* __restrict__ xtc){
  const int n1 = NB*DI*LL;
  int idx = blockIdx.x*256 + threadIdx.x;
  if (idx >= 2*n1) return;
  int isXT = idx >= n1;
  int id = isXT ? idx - n1 : idx;
  int l = id % LL; int d = (id / LL) % DI; int b = id / (DI*LL);
  int h = l / WW, wp = l % WW;
  const float* src; const float* wk; float acc;
  if (!isXT){
    src = xz + ((size_t)b*384 + d)*LL;
    wk = c2w + d*9; acc = c2b[d];
  } else {
    src = xtT + ((size_t)b*96 + (d >> 1))*LL;
    wk = cxw + d*9; acc = cxb[d];
  }
  #pragma unroll
  for (int dh = 0; dh < 3; ++dh){
    int hh = h + dh - 1; if (hh < 0 || hh >= HH) continue;
    const float* row = src + hh*WW;
    #pragma unroll
    for (int dw = 0; dw < 3; ++dw){
      int wq = wp + dw - 1; if (wq < 0 || wq >= WW) continue;
      acc += wk[dh*3+dw] * row[wq];
    }
  }
  (isXT ? xtc : xc)[((size_t)b*DI + d)*LL + l] = siluf(acc);
}

// ---------------- K4: pools -> 2 directional base sequences ----------------
__global__ __launch_bounds__(256) void k_xs(const float* __restrict__ xc,
                                            const float* __restrict__ xtc,
                                            float* __restrict__ xs){
  __shared__ float T[4][32][57];
  int h = blockIdx.x, b = blockIdx.y, dt = blockIdx.z;
  int d0 = dt*32;
  int i0 = (h >> 1) * 2;
  const float* rsrc = (h & 1) ? xtc : xc;
  for (int i = threadIdx.x; i < 4*32*56; i += 256){
    int pl = i / (32*56); int r = i % (32*56); int dl = r / 56; int w = r % 56;
    const float* s; int row;
    if (pl == 0){ s = xc;  row = h; }
    else if (pl == 1){ s = xtc; row = h; }
    else if (pl == 2){ s = rsrc; row = i0; }
    else { s = rsrc; row = i0 + 1; }
    T[pl][dl][w] = s[((size_t)b*DI + d0 + dl)*LL + row*WW + w];
  }
  __syncthreads();
  for (int o = threadIdx.x; o < 2*56*32; o += 256){
    int out = o / (56*32); int r = o % (56*32); int wp = r / 32; int dl = r & 31;
    if (out == 1){
      int s = wp & 1; int w0 = (wp >> 1) * 2;
      float a0 = T[s][dl][w0], a1 = T[s][dl][w0+1];
      float ic = 0.5f*(a0+a1) + fmaxf(a0,a1);
      xs[(((size_t)b*2 + 1)*LL + h*WW + wp)*DI + d0 + dl] = ic;
    } else {
      float r0 = T[2][dl][wp], r1 = T[3][dl][wp];
      float ir = 0.5f*(r0+r1) + fmaxf(r0,r1);
      xs[(((size_t)b*2 + 0)*LL + wp*HH + h)*DI + d0 + dl] = ir;
    }
  }
}

// ---------------- K5a: kernel_diff ----------------
__global__ __launch_bounds__(256) void k_kd(const float* __restrict__ xpw, float* __restrict__ kd){
  int idx = blockIdx.x*256 + threadIdx.x;
  if (idx >= NKO*DI) return;
  const float* p = xpw + (size_t)idx*18;
  float s = 0.f;
  #pragma unroll
  for (int i = 0; i < 18; ++i) s += p[i];
  kd[idx] = s;
}

// ---------------- K5b: pack weights + A-border zero + opw transpose (fused ranges) ----------------
__global__ __launch_bounds__(256) void k_wpack(const float* __restrict__ xpw,
                                               const float* __restrict__ kd,
                                               const float* __restrict__ opw,
                                               unsigned short* __restrict__ Bp,
                                               unsigned short* __restrict__ Bd,
                                               unsigned short* __restrict__ Ah,
                                               unsigned short* __restrict__ Al,
                                               float* __restrict__ opwT){
  int idx = blockIdx.x*256 + threadIdx.x;
  if (idx < BPELEMS){
    int q = idx & 31; int n = (idx >> 5) % NPAD; int oks = idx / (NPAD*32);
    int ks = oks % 12, off = oks / 12;
    int k = ks*32 + q;
    int t = k / DI, c = k % DI;
    float v = 0.f;
    if (n < NKO){
      float w = xpw[((size_t)(n*DI + c)*2 + t)*9 + off];
      v = 2.f*w;
      if (off == 4) v -= THETA_C * kd[n*DI + c];
    }
    unsigned short hi, lo; split_bf16(v, hi, lo);
    Bp[idx] = hi; Bp[BPELEMS + idx] = lo;
    return;
  }
  int id2 = idx - BPELEMS;
  if (id2 < BDELEMS){
    int q = id2 & 31; int n = (id2 >> 5) % NPAD; int ks = id2 / (NPAD*32);
    int k = ks*32 + q;
    int t = k / DI, c = k % DI;
    float v = 0.f;
    if (n < NKO){
      float kv = kd[n*DI + c];
      v = (t == 0) ? kv : -kv;
    }
    unsigned short hi, lo; split_bf16(v, hi, lo);
    Bd[id2] = hi; Bd[BDELEMS + id2] = lo;
    return;
  }
  int id3 = id2 - BDELEMS;
  if (id3 < AZTOT){
    int arr = id3 / (AZTOT/2); int r = id3 % (AZTOT/2);
    int k8 = r % 96; r /= 96;
    int b = r / 228; int pi = r % 228;
    int row, col;
    if (pi < 58){ row = 0; col = pi; }
    else if (pi < 116){ row = 57; col = pi - 58; }
    else if (pi < 172){ row = pi - 115; col = 0; }
    else { row = pi - 171; col = 57; }
    unsigned short* p = (arr ? Al : Ah) + ((size_t)b*PIXP + (size_t)row*HP + col)*KK + k8*4;
    *(unsigned long long*)p = 0ULL;
    return;
  }
  int id4 = id3 - AZTOT;
  if (id4 < TOPWN){
    int d = id4 / DI, dd = id4 % DI;
    opwT[dd*96 + d] = opw[id4];
  }
}

// ---------------- K5c: pack A ----------------
__global__ __launch_bounds__(256) void k_apack(const float* __restrict__ xc,
                                               const float* __restrict__ xtc,
                                               unsigned short* __restrict__ Ah,
                                               unsigned short* __restrict__ Al){
  __shared__ float tile[64*57];
  int h = blockIdx.x, b = blockIdx.y, z = blockIdx.z;
  int t = z / 3, cc = z % 3;
  const float* src = (t ? xtc : xc) + (size_t)b*DI*LL;
  for (int i = threadIdx.x; i < 64*56; i += 256){
    int ci = i / 56, wpx = i % 56;
    tile[ci*57 + wpx] = src[(size_t)(cc*64 + ci)*LL + h*WW + wpx];
  }
  __syncthreads();
  int cl = threadIdx.x & 63, wv = threadIdx.x >> 6;
  for (int wp = wv; wp < WW; wp += 4){
    float v = tile[cl*57 + wp];
    unsigned short hi, lo; split_bf16(v, hi, lo);
    size_t eo = ((size_t)b*PIXP + (size_t)(h+1)*HP + (wp+1))*KK + t*DI + cc*64 + cl;
    Ah[eo] = hi; Al[eo] = lo;
  }
}

// ---------------- K5d: MFMA GEMM v5 — 4-wave blocks, B staged in LDS ----------------
// grid (49, 8): mg = 128-pixel group; y<6: og=y>>1 (offsets 3og..3og+2), ch=y&1 -> parts[og]
//               y>=6: diff (center tap), ch=y&1 -> parts[3]
// Per block: 6 stages (diff: 2) x { stage B (6ks x hi/lo x 5nf = 60KB) -> 6 K-steps x 30 MFMA/wave }
__global__ __launch_bounds__(256) void k_gemm(const unsigned short* __restrict__ Ah,
                                              const unsigned short* __restrict__ Al,
                                              const unsigned short* __restrict__ Bp,
                                              const unsigned short* __restrict__ Bd,
                                              float* __restrict__ parts){
  __shared__ short Bs[60*512];   // 60 frags x 1KB
  int tid = threadIdx.x;
  int lane = tid & 63, wave = tid >> 6;
  int cl = lane & 15, kg = lane >> 4;
  int mg = blockIdx.x;
  int y = blockIdx.y;
  bool isDiff = (y >= 6);
  int ch = y & 1;
  int og = y >> 1;               // 0..2 linear, 3 diff
  int col = ch*80 + cl;

  // per-lane A base (unshifted field pixel) for the wave's 2 m-frags
  size_t aoff[2];
  #pragma unroll
  for (int mi = 0; mi < 2; ++mi){
    int p = mg*128 + (wave*2 + mi)*16 + cl;
    int b = p / LL, l = p % LL;
    int h = l / WW, wp = l % WW;
    aoff[mi] = ((size_t)b*PIXP + (size_t)h*HP + wp)*KK + kg*8;
  }

  f4v acc[2][5];
  #pragma unroll
  for (int mi = 0; mi < 2; ++mi)
    #pragma unroll
    for (int nf = 0; nf < 5; ++nf) acc[mi][nf] = (f4v){0.f,0.f,0.f,0.f};

  const int nStages = isDiff ? 2 : 6;
  for (int st = 0; st < nStages; ++st){
    int oo = st >> 1;                       // linear: offset index within og
    int kh = st & 1;                        // linear: which 6-ks half
    int off = 3*og + oo;                    // linear only
    int ksBase = isDiff ? st*6 : (off*12 + kh*6);
    const unsigned short* Bh = isDiff ? Bd : Bp;
    size_t loSkip = isDiff ? (size_t)BDELEMS : (size_t)BPELEMS;

    __syncthreads();
    #pragma unroll
    for (int i = 0; i < 15; ++i){
      int slot = tid + 256*i;
      int fi = slot >> 6, lv = slot & 63;
      int cl2 = lv & 15, kg2 = lv >> 4;
      int ksl = fi / 10, r = fi % 10;
      int hl = r / 5, nf = r % 5;
      size_t gs = ((size_t)(ksBase + ksl)*NPAD + ch*80 + nf*16 + cl2)*32 + kg2*8
                + (hl ? loSkip : 0);
      *(s8v*)(Bs + fi*512 + lv*8) = *(const s8v*)(Bh + gs);
    }
    __syncthreads();

    size_t ashift = isDiff ? (size_t)(HP + 1)*KK
                           : (size_t)((off/3)*HP + (off%3))*KK;
    int ks0 = isDiff ? st*6 : kh*6;
    #pragma unroll 2
    for (int ksl = 0; ksl < 6; ++ksl){
      s8v bh[5], bl[5];
      #pragma unroll
      for (int nf = 0; nf < 5; ++nf){
        bh[nf] = *(const s8v*)(Bs + (ksl*10 + nf)*512 + lane*8);
        bl[nf] = *(const s8v*)(Bs + (ksl*10 + 5 + nf)*512 + lane*8);
      }
      #pragma unroll
      for (int mi = 0; mi < 2; ++mi){
        size_t ao = aoff[mi] + ashift + (size_t)(ks0 + ksl)*32;
        s8v ahv = *(const s8v*)(Ah + ao);
        s8v alv = *(const s8v*)(Al + ao);
        #pragma unroll
        for (int nf = 0; nf < 5; ++nf)
          acc[mi][nf] = __builtin_amdgcn_mfma_f32_16x16x32_bf16(ahv, bh[nf], acc[mi][nf], 0, 0, 0);
        #pragma unroll
        for (int nf = 0; nf < 5; ++nf)
          acc[mi][nf] = __builtin_amdgcn_mfma_f32_16x16x32_bf16(alv, bh[nf], acc[mi][nf], 0, 0, 0);
        #pragma unroll
        for (int nf = 0; nf < 5; ++nf)
          acc[mi][nf] = __builtin_amdgcn_mfma_f32_16x16x32_bf16(ahv, bl[nf], acc[mi][nf], 0, 0, 0);
      }
    }
  }

  int q = isDiff ? 3 : og;
  float* part = parts + (size_t)q*PSZ;
  #pragma unroll
  for (int mi = 0; mi < 2; ++mi){
    int prow0 = mg*128 + (wave*2 + mi)*16 + kg*4;
    #pragma unroll
    for (int nf = 0; nf < 5; ++nf){
      int c2 = col + nf*16;
      #pragma unroll
      for (int i = 0; i < 4; ++i)
        part[(size_t)(prow0 + i)*NPAD + c2] = acc[mi][nf][i];
    }
  }
}

// ---------------- K5e: combine partials -> pooled ----------------
__global__ __launch_bounds__(256) void k_pool(const float* __restrict__ parts,
                                              float* __restrict__ pooled){
  int idx = blockIdx.x*256 + threadIdx.x;
  if (idx >= NB*LL*NKO) return;
  int ko = idx % NKO; int l = idx / NKO;
  size_t e = (size_t)l*NPAD + ko;
  float lin = parts[e] + parts[PSZ + e] + parts[2*PSZ + e];
  float dv = parts[3*PSZ + e];
  float pv = lin + 0.5f*THETA_C*fabsf(dv);
  int b = l / LL, ll = l % LL;
  int k = ko / NCOUT, o = ko % NCOUT;
  pooled[(((size_t)b*4 + k)*LL + ll)*NCOUT + o] = pv;
}

// ---------------- K6a: scan pass A ----------------
__global__ __launch_bounds__(64) void k_scanA(const float* __restrict__ pooled,
                                              const float* __restrict__ xs,
                                              const float* __restrict__ dtw,
                                              const float* __restrict__ dtb,
                                              const float* __restrict__ alog,
                                              float* __restrict__ Pb,
                                              float* __restrict__ He){
  int d = blockIdx.z*64 + threadIdx.x;
  int bk = blockIdx.y;
  int c = blockIdx.x;
  int k = bk & 3, b = bk >> 2;
  int kdix = k*DI + d;
  int dir = (k >> 1) & 1;
  int flip = k & 1;
  float A[NST], P[NST], hst[NST];
  #pragma unroll
  for (int n = 0; n < NST; ++n){ A[n] = -__expf(alog[kdix*NST + n]); P[n] = 1.f; hst[n] = 0.f; }
  float dwv[NDTR];
  #pragma unroll
  for (int r = 0; r < NDTR; ++r) dwv[r] = dtw[kdix*NDTR + r];
  float db = dtb[kdix];
  const float* prow = pooled + ((size_t)bk*LL + c*CLEN)*NCOUT;
  const float* xsd = xs + ((size_t)(b*2 + dir)*LL)*DI + d;
  int pos = c*CLEN;
  int wp = pos % 56, rowb = pos - wp;
  for (int p = 0; p < CLEN; ++p){
    float xr = db;
    #pragma unroll
    for (int r = 0; r < NDTR; ++r) xr += prow[r]*dwv[r];
    float delta = softplusf(xr);
    int upos = flip ? (rowb + 55 - wp) : pos;
    float u = xsd[(size_t)upos*DI];
    float du = delta * u;
    #pragma unroll
    for (int n = 0; n < NST; ++n){
      float dA = __expf(delta * A[n]);
      P[n]  *= dA;
      hst[n] = dA*hst[n] + du*prow[6+n];
    }
    prow += NCOUT;
    ++pos; ++wp; if (wp == 56){ wp = 0; rowb = pos; }
  }
  float* pp = Pb + (((size_t)bk*NCH + c)*DI + d)*NST;
  float* hp = He + (((size_t)bk*NCH + c)*DI + d)*NST;
  #pragma unroll
  for (int n = 0; n < NST; ++n){ pp[n] = P[n]; hp[n] = hst[n]; }
}

// ---------------- K6b: cross-chunk prefix ----------------
__global__ __launch_bounds__(256) void k_scanB(const float* __restrict__ Pb,
                                               const float* __restrict__ He,
                                               float* __restrict__ H0){
  int t = blockIdx.x*256 + threadIdx.x;
  if (t >= NB*4*DI*NST) return;
  int bk = t / (DI*NST);
  int dn = t % (DI*NST);
  float hcur = 0.f;
  for (int c = 0; c < NCH; ++c){
    size_t off = ((size_t)bk*NCH + c)*DI*NST + dn;
    H0[off] = hcur;
    hcur = Pb[off]*hcur + He[off];
  }
}

// ---------------- K6c: scan pass C ----------------
__global__ __launch_bounds__(64) void k_scanC(const float* __restrict__ pooled,
                                              const float* __restrict__ xs,
                                              const float* __restrict__ dtw,
                                              const float* __restrict__ dtb,
                                              const float* __restrict__ alog,
                                              const float* __restrict__ Dsv,
                                              const float* __restrict__ H0,
                                              float* __restrict__ oy){
  int d = blockIdx.z*64 + threadIdx.x;
  int bk = blockIdx.y;
  int c = blockIdx.x;
  int k = bk & 3, b = bk >> 2;
  int kdix = k*DI + d;
  int dir = (k >> 1) & 1;
  int flip = k & 1;
  float A[NST], hst[NST];
  const float* h0p = H0 + (((size_t)bk*NCH + c)*DI + d)*NST;
  #pragma unroll
  for (int n = 0; n < NST; ++n){ A[n] = -__expf(alog[kdix*NST + n]); hst[n] = h0p[n]; }
  float dwv[NDTR];
  #pragma unroll
  for (int r = 0; r < NDTR; ++r) dwv[r] = dtw[kdix*NDTR + r];
  float db = dtb[kdix];
  float Dv = Dsv[kdix];
  const float* prow = pooled + ((size_t)bk*LL + c*CLEN)*NCOUT;
  const float* xsd = xs + ((size_t)(b*2 + dir)*LL)*DI + d;
  float* orow = oy + ((size_t)bk*LL + c*CLEN)*DI + d;
  int pos = c*CLEN;
  int wp = pos % 56, rowb = pos - wp;
  for (int p = 0; p < CLEN; ++p){
    float xr = db;
    #pragma unroll
    for (int r = 0; r < NDTR; ++r) xr += prow[r]*dwv[r];
    float delta = softplusf(xr);
    int upos = flip ? (rowb + 55 - wp) : pos;
    float u = xsd[(size_t)upos*DI];
    float du = delta * u;
    float y = 0.f;
    #pragma unroll
    for (int n = 0; n < NST; ++n){
      float dA = __expf(delta * A[n]);
      hst[n] = dA*hst[n] + du*prow[6+n];
      y += hst[n]*prow[22+n];
    }
    orow[0] = y + Dv*u;
    prow += NCOUT; orow += DI;
    ++pos; ++wp; if (wp == 56){ wp = 0; rowb = pos; }
  }
}

// ---------------- K7: merge + LN + gate + out_proj (split dot) ----------------
__global__ __launch_bounds__(192) void k_out(const float* __restrict__ oy,
                                             const float* __restrict__ xz,
                                             const float* __restrict__ lng,
                                             const float* __restrict__ lnb,
                                             const float* __restrict__ opwT,
                                             float* __restrict__ out){
  __shared__ float ygs[DI];
  __shared__ float pacc[96];
  __shared__ float redS[3], redQ[3];
  int bl = blockIdx.x; int b = bl / LL; int l = bl % LL;
  int d = threadIdx.x;
  int h = l / WW, wp = l % WW;
  int p2 = wp*HH + h;
  size_t b4 = (size_t)b*4;
  float y = oy[((b4+0)*LL + l)*DI + d]
          + oy[((b4+2)*LL + (LL-1-l))*DI + d]
          + oy[((b4+1)*LL + p2)*DI + d]
          + oy[((b4+3)*LL + (LL-1-p2))*DI + d];
  float s = y, q = y*y;
  #pragma unroll
  for (int m = 1; m < 64; m <<= 1){ s += __shfl_xor(s, m); q += __shfl_xor(q, m); }
  int wv = d >> 6;
  if ((d & 63) == 0){ redS[wv] = s; redQ[wv] = q; }
  __syncthreads();
  float S = redS[0]+redS[1]+redS[2];
  float Q = redQ[0]+redQ[1]+redQ[2];
  float mu = S * (1.f/DI);
  float var = Q * (1.f/DI) - mu*mu;
  float yn = (y - mu) * rsqrtf(var + 1e-5f) * lng[d] + lnb[d];
  float zv = xz[((size_t)b*384 + 192 + d)*LL + l];
  ygs[d] = yn * siluf(zv);
  __syncthreads();
  int half = d / 96, dc = d - half*96;
  float acc = 0.f;
  int dd0 = half * 96;
  #pragma unroll 8
  for (int dd = dd0; dd < dd0 + 96; ++dd) acc += ygs[dd] * opwT[dd*96 + dc];
  if (half) pacc[dc] = acc;
  __syncthreads();
  if (!half) out[(size_t)bl*96 + dc] = acc + pacc[dc];
}

extern "C" void kernel_launch(void* const* d_in, const int* in_sizes, int n_in,
                              void* d_out, int out_size, void* d_ws, size_t ws_size,
                              hipStream_t stream){
  const float* x    = (const float*)d_in[0];
  const float* xt   = (const float*)d_in[1];
  const float* ipw  = (const float*)d_in[2];
  const float* c2w  = (const float*)d_in[3];
  const float* c2b  = (const float*)d_in[4];
  const float* cxw  = (const float*)d_in[5];
  const float* cxb  = (const float*)d_in[6];
  const float* xpw  = (const float*)d_in[7];
  const float* dtw  = (const float*)d_in[8];
  const float* dtb  = (const float*)d_in[9];
  const float* alog = (const float*)d_in[10];
  const float* Dsv  = (const float*)d_in[11];
  const float* lng  = (const float*)d_in[12];
  const float* lnb  = (const float*)d_in[13];
  const float* opw  = (const float*)d_in[14];
  float* out = (float*)d_out;

  float* ws   = (float*)d_ws;
  float* xz   = ws;
  float* xc   = xz  + (size_t)NB*384*LL;
  float* xtc  = xc  + (size_t)NB*DI*LL;
  float* xs   = xtc + (size_t)NB*DI*LL;
  float* pool = xs  + (size_t)NB*2*LL*DI;
  float* kd   = pool+ (size_t)NB*4*LL*NCOUT;
  float* opwT = kd  + (size_t)NKO*DI;
  float* U1   = opwT + (size_t)96*DI;
  float* Pb   = U1;
  float* He   = Pb  + (size_t)NB*4*NCH*DI*NST;
  float* H0   = He  + (size_t)NB*4*NCH*DI*NST;
  unsigned short* Ahi = (unsigned short*)U1;
  unsigned short* Alo = Ahi + AELEMS;
  unsigned short* Bp  = Alo + AELEMS;
  unsigned short* Bd  = Bp + 2*BPELEMS;
  float* U2   = U1 + 3*(size_t)NB*4*NCH*DI*NST;
  float* parts = U2;          // 4 x PSZ
  float* oy    = U2;
  float* xtT   = U2 + 4*PSZ;  // alias beyond parts; gemm writes only after conv consumed xtT

  k_inproj<<<NB*LL/16, 512, 0, stream>>>(x, ipw, xz);
  k_txt<<<dim3(LL/16, NB), 256, 0, stream>>>(xt, xtT);
  k_kd<<<(NKO*DI+255)/256, 256, 0, stream>>>(xpw, kd);
  k_wpack<<<(BPELEMS+BDELEMS+AZTOT+TOPWN+255)/256, 256, 0, stream>>>(xpw, kd, opw, Bp, Bd, Ahi, Alo, opwT);
  int n1 = NB*DI*LL;
  k_conv<<<(2*n1+255)/256, 256, 0, stream>>>(xz, xtT, c2w, c2b, cxw, cxb, xc, xtc);
  k_xs<<<dim3(HH, NB, 6), 256, 0, stream>>>(xc, xtc, xs);
  k_apack<<<dim3(HH, NB, 6), 256, 0, stream>>>(xc, xtc, Ahi, Alo);
  k_gemm<<<dim3(49, 8), 256, 0, stream>>>(Ahi, Alo, Bp, Bd, parts);
  k_pool<<<(NB*LL*NKO+255)/256, 256, 0, stream>>>(parts, pool);
  k_scanA<<<dim3(NCH, NB*4, 3), 64, 0, stream>>>(pool, xs, dtw, dtb, alog, Pb, He);
  k_scanB<<<(NB*4*DI*NST+255)/256, 256, 0, stream>>>(Pb, He, H0);
  k_scanC<<<dim3(NCH, NB*4, 3), 64, 0, stream>>>(pool, xs, dtw, dtb, alog, Dsv, H0, oy);
  k_out<<<NB*LL, 192, 0, stream>>>(oy, xz, lng, lnb, opwT, out);
}